// Round 1
// baseline (587.815 us; speedup 1.0000x reference)
//
#include <hip/hip_runtime.h>
#include <hip/hip_bf16.h>

#define B_    1024
#define NHID_ 4096
#define NBO   8
#define BSO   512
#define DK_   64

typedef __bf16 bf16;
typedef __bf16 bf16x4 __attribute__((ext_vector_type(4)));
typedef __bf16 bf16x8 __attribute__((ext_vector_type(8)));
typedef float  f32x4  __attribute__((ext_vector_type(4)));

__device__ __forceinline__ float sigf(float x){ return 1.0f/(1.0f + __expf(-x)); }

// ---------------------------------------------------------------- K0a: hx -> bf16
__global__ __launch_bounds__(256) void k_conv_hx(const float* __restrict__ hx,
                                                 bf16* __restrict__ hb16)
{
    int i = blockIdx.x*blockDim.x + threadIdx.x;
    int stride = gridDim.x*blockDim.x;
    const float4* in4 = (const float4*)hx;
    for (int idx = i; idx < (B_*NHID_/4); idx += stride){
        float4 v = in4[idx];
        bf16x4 o; o.x=(bf16)v.x; o.y=(bf16)v.y; o.z=(bf16)v.z; o.w=(bf16)v.w;
        *(bf16x4*)&hb16[(size_t)idx*4] = o;
    }
}

// ------------------------------------- K0b: w_ih/w_hh -> bf16, transposed [n][col][k]
// wT[n][col][k]: k<512 from w_ih[n][k][col], k>=512 from w_hh[n][k-512][col]
__global__ __launch_bounds__(256) void k_wtrans(const float* __restrict__ w_ih,
                                                const float* __restrict__ w_hh,
                                                bf16* __restrict__ wT)
{
    int n = blockIdx.z >> 1, which = blockIdx.z & 1;
    int k0 = blockIdx.y * 64, c0 = blockIdx.x * 64;
    const float* src = (which ? w_hh : w_ih) + (size_t)n*512*2048;
    __shared__ float tile[64][65];
    int t = threadIdx.x;
    for (int i = t; i < 4096; i += 256){
        int r = i >> 6, c = i & 63;
        tile[r][c] = src[(size_t)(k0+r)*2048 + (c0+c)];
    }
    __syncthreads();
    for (int i = t; i < 4096; i += 256){
        int c = i >> 6, r = i & 63;
        wT[((size_t)n*2048 + (c0+c))*1024 + which*512 + k0 + r] = (bf16)tile[r][c];
    }
}

// ---------------------------------------------------------------- K1: input attention + mask
__global__ __launch_bounds__(256) void k_attn_in(
    const float* __restrict__ inp, const float* __restrict__ hx,
    const float* __restrict__ ia_wq, const float* __restrict__ ia_wk,
    const float* __restrict__ ia_wv, const float* __restrict__ ia_fc_w,
    const float* __restrict__ ia_fc_b,
    bf16* __restrict__ xb16, float* __restrict__ maskb, float* __restrict__ mask_out)
{
    int b = blockIdx.x, t = threadIdx.x;
    __shared__ float x_s[512];
    __shared__ float hb_s[4096];
    __shared__ float q_s[512];
    __shared__ float k_s[320];
    __shared__ float v_s[320];
    __shared__ float attn_s[40];
    __shared__ float score_s[8];
    __shared__ float mb_s[8];
    __shared__ float o_s[512];

    for (int i=t;i<512;i+=256) x_s[i] = inp[(size_t)b*512+i];
    const float4* h4 = (const float4*)(hx + (size_t)b*4096);
    for (int i=t;i<1024;i+=256) ((float4*)hb_s)[i] = h4[i];
    __syncthreads();

    // q = hb @ ia_wq  (per block n: 512x64)
    for (int i=t;i<512;i+=256){
        int nn=i>>6, e=i&63;
        const float* w = ia_wq + (size_t)nn*512*64 + e;
        const float* h = hb_s + nn*512;
        float s0=0.f,s1=0.f,s2=0.f,s3=0.f;
        for (int d=0; d<512; d+=4){
            s0 += h[d+0]*w[(size_t)(d+0)*64];
            s1 += h[d+1]*w[(size_t)(d+1)*64];
            s2 += h[d+2]*w[(size_t)(d+2)*64];
            s3 += h[d+3]*w[(size_t)(d+3)*64];
        }
        q_s[i]=(s0+s1)+(s2+s3);
    }
    // k, v (input blocks 0..3; block 4 is zeros)
    {
        int nn=t>>6, e=t&63;
        const float* wk = ia_wk + (size_t)nn*128*64 + e;
        const float* wv = ia_wv + (size_t)nn*128*64 + e;
        const float* xx = x_s + nn*128;
        float sk=0.f, sv=0.f;
        for (int d=0; d<128; ++d){ float xv=xx[d]; sk += xv*wk[(size_t)d*64]; sv += xv*wv[(size_t)d*64]; }
        k_s[t]=sk; v_s[t]=sv;
        if (t<64){ k_s[256+t]=0.f; v_s[256+t]=0.f; }
    }
    __syncthreads();
    if (t<40){
        int nn=t/5, j=t%5;
        float s=0.f;
        for (int e=0;e<64;++e) s += q_s[nn*64+e]*k_s[j*64+e];
        attn_s[t] = s*0.125f;   // 1/sqrt(64)
    }
    __syncthreads();
    if (t<8){
        float m=attn_s[t*5];
        for (int j=1;j<5;++j) m=fmaxf(m, attn_s[t*5+j]);
        float ex[5]; float sum=0.f;
        for (int j=0;j<5;++j){ ex[j]=__expf(attn_s[t*5+j]-m); sum+=ex[j]; }
        float inv = 1.f/sum;
        for (int j=0;j<5;++j) attn_s[t*5+j] = ex[j]*inv;
        score_s[t] = ex[0]*inv;
    }
    __syncthreads();
    for (int i=t;i<512;i+=256){
        int nn=i>>6, e=i&63;
        float s=0.f;
        #pragma unroll
        for (int j=0;j<5;++j) s += attn_s[nn*5+j]*v_s[j*64+e];
        o_s[i]=s;
    }
    if (t==0){
        float s[8];
        for (int nn=0;nn<8;++nn) s[nn]=score_s[nn];
        for (int ii=1;ii<8;++ii){ float key=s[ii]; int j=ii-1;
            while(j>=0 && s[j]<key){ s[j+1]=s[j]; --j; } s[j+1]=key; }
        float thr = s[3]-0.01f;   // 4th largest - 0.01
        for (int nn=0;nn<8;++nn) mb_s[nn] = (score_s[nn] > thr) ? 1.0f : 0.0f;
    }
    __syncthreads();
    // inp_use = o @ ia_fc_w + b -> bf16 (GEMM A-operand), plus mask outputs
    for (int i=t;i<4096;i+=256){
        int nn=i>>9, dd=i&511;
        float s0 = ia_fc_b[dd], s1 = 0.f;
        const float* o = o_s + nn*64;
        for (int e=0;e<64;e+=2){
            s0 += o[e+0]*ia_fc_w[(e+0)*512+dd];
            s1 += o[e+1]*ia_fc_w[(e+1)*512+dd];
        }
        float s = s0+s1;
        xb16[(size_t)b*4096 + i] = (bf16)s;
        mask_out[(size_t)b*4096 + i] = mb_s[nn];
    }
    if (t<8) maskb[b*8+t] = mb_s[t];
}

// ---------------------------------------------------------------- K2: LSTM gates MFMA + pointwise
// grid: (x=16 Mtiles of 64 rows, y=8 dtiles of 64 cols, z=8 blocks n), block 256 (4 waves, 2x2)
__global__ __launch_bounds__(256) void k_lstm(
    const bf16* __restrict__ xb16, const bf16* __restrict__ hb16,
    const bf16* __restrict__ wT, const float* __restrict__ b_ih,
    const float* __restrict__ b_hh, const float* __restrict__ cx,
    const float* __restrict__ maskb,
    float* __restrict__ cx_out, float* __restrict__ hnew)
{
    int n  = blockIdx.z;
    int b0 = blockIdx.x * 64;
    int d0 = blockIdx.y * 64;
    int t  = threadIdx.x;
    int wave = t >> 6, lane = t & 63;
    int quad = lane >> 4, l16 = lane & 15;
    int wm = wave & 1, wd = wave >> 1;

    __shared__ bf16 A_s[64*32];       // [row][k], 64B rows
    __shared__ bf16 W_s[4][64*32];    // per gate: [colLocal][k]

    f32x4 zero = {0.f,0.f,0.f,0.f};
    f32x4 acc[4][2][2];
    #pragma unroll
    for (int g=0;g<4;++g)
        #pragma unroll
        for(int r=0;r<2;++r)
            #pragma unroll
            for(int c=0;c<2;++c) acc[g][r][c] = zero;

    int arow = t >> 2;    // 0..63 (A row / W colLocal)
    int aseg = t & 3;     // 16B segment within 32 k
    const bf16* wbase = wT + ((size_t)n*2048 + d0)*1024;

    for (int k0 = 0; k0 < 1024; k0 += 32){
        const bf16* asrc = (k0 < 512)
            ? xb16 + (size_t)(b0+arow)*4096 + n*512 + k0 + aseg*8
            : hb16 + (size_t)(b0+arow)*4096 + n*512 + (k0-512) + aseg*8;
        *(bf16x8*)&A_s[arow*32 + aseg*8] = *(const bf16x8*)asrc;
        #pragma unroll
        for (int g=0; g<4; ++g){
            const bf16* wsrc = wbase + (size_t)(g*512 + arow)*1024 + k0 + aseg*8;
            *(bf16x8*)&W_s[g][arow*32 + aseg*8] = *(const bf16x8*)wsrc;
        }
        __syncthreads();
        bf16x8 a0 = *(const bf16x8*)&A_s[(wm*32      + l16)*32 + quad*8];
        bf16x8 a1 = *(const bf16x8*)&A_s[(wm*32 + 16 + l16)*32 + quad*8];
        #pragma unroll
        for (int g=0; g<4; ++g){
            bf16x8 bb0 = *(const bf16x8*)&W_s[g][(wd*32      + l16)*32 + quad*8];
            bf16x8 bb1 = *(const bf16x8*)&W_s[g][(wd*32 + 16 + l16)*32 + quad*8];
            acc[g][0][0] = __builtin_amdgcn_mfma_f32_16x16x32_bf16(a0, bb0, acc[g][0][0], 0,0,0);
            acc[g][0][1] = __builtin_amdgcn_mfma_f32_16x16x32_bf16(a0, bb1, acc[g][0][1], 0,0,0);
            acc[g][1][0] = __builtin_amdgcn_mfma_f32_16x16x32_bf16(a1, bb0, acc[g][1][0], 0,0,0);
            acc[g][1][1] = __builtin_amdgcn_mfma_f32_16x16x32_bf16(a1, bb1, acc[g][1][1], 0,0,0);
        }
        __syncthreads();
    }

    // epilogue: gates + biases -> LSTM pointwise, fused in registers
    #pragma unroll
    for (int c=0;c<2;++c){
        int col = wd*32 + c*16 + l16;
        int d   = d0 + col;
        float bi  = b_ih[n*2048 +        d] + b_hh[n*2048 +        d];
        float bff = b_ih[n*2048 +  512 + d] + b_hh[n*2048 +  512 + d];
        float bg  = b_ih[n*2048 + 1024 + d] + b_hh[n*2048 + 1024 + d];
        float bo  = b_ih[n*2048 + 1536 + d] + b_hh[n*2048 + 1536 + d];
        #pragma unroll
        for (int r=0;r<2;++r){
            #pragma unroll
            for (int v=0; v<4; ++v){
                int row = wm*32 + r*16 + quad*4 + v;
                int bb  = b0 + row;
                float gi = acc[0][r][c][v] + bi;
                float gf = acc[1][r][c][v] + bff;
                float gg = acc[2][r][c][v] + bg;
                float go = acc[3][r][c][v] + bo;
                size_t gidx = (size_t)bb*4096 + n*512 + d;
                float cb = cx[gidx];
                float cn = sigf(gf)*cb + sigf(gi)*tanhf(gg);
                float hn = sigf(go)*tanhf(cn);
                float m  = maskb[bb*8+n];
                cx_out[gidx] = (m != 0.f) ? cn : cb;
                hnew[gidx]   = hn;
            }
        }
    }
}

// ---------------------------------------------------------------- K3: output MHA + residual + mask
__global__ __launch_bounds__(256) void k_mha_out(
    const float* __restrict__ hnew, const float* __restrict__ hx,
    const float* __restrict__ wq, const float* __restrict__ wk,
    const float* __restrict__ wv, const float* __restrict__ fc_w,
    const float* __restrict__ fc_b, const float* __restrict__ gate_w,
    const float* __restrict__ gate_b, const float* __restrict__ maskb,
    float* __restrict__ hx_out)
{
    int b = blockIdx.x, t = threadIdx.x;
    __shared__ float hn_s[4096];
    __shared__ float q_s[512], k_s[512], v_s[512];
    __shared__ float attn_s[64];
    __shared__ float o_s[512];
    const float4* h4 = (const float4*)(hnew + (size_t)b*4096);
    for (int i=t;i<1024;i+=256) ((float4*)hn_s)[i] = h4[i];
    __syncthreads();
    for (int i=t;i<512;i+=256){
        int nn=i>>6, e=i&63;
        const float* h  = hn_s + nn*512;
        const float* pq = wq + (size_t)nn*32768 + e;
        const float* pk = wk + (size_t)nn*32768 + e;
        const float* pv = wv + (size_t)nn*32768 + e;
        float sq=0.f, sk=0.f, sv=0.f;
        for (int d=0; d<512; ++d){
            float hv=h[d];
            sq += hv*pq[(size_t)d*64];
            sk += hv*pk[(size_t)d*64];
            sv += hv*pv[(size_t)d*64];
        }
        q_s[i]=sq; k_s[i]=sk; v_s[i]=sv;
    }
    __syncthreads();
    if (t<64){
        int nn=t>>3, j=t&7;
        float s=0.f;
        for (int e=0;e<64;++e) s += q_s[nn*64+e]*k_s[j*64+e];
        attn_s[t]=s*0.125f;
    }
    __syncthreads();
    if (t<8){
        float m=attn_s[t*8];
        for (int j=1;j<8;++j) m=fmaxf(m,attn_s[t*8+j]);
        float ex[8]; float sum=0.f;
        for (int j=0;j<8;++j){ ex[j]=__expf(attn_s[t*8+j]-m); sum+=ex[j]; }
        float inv=1.f/sum;
        for (int j=0;j<8;++j) attn_s[t*8+j]=ex[j]*inv;
    }
    __syncthreads();
    for (int i=t;i<512;i+=256){
        int nn=i>>6, e=i&63;
        float s=0.f;
        #pragma unroll
        for (int j=0;j<8;++j) s += attn_s[nn*8+j]*v_s[j*64+e];
        o_s[i]=s;
    }
    __syncthreads();
    for (int i=t;i<4096;i+=256){
        int nn=i>>9, dd=i&511;
        float so=fc_b[dd], sg=gate_b[dd];
        const float* o=o_s+nn*64;
        for (int e=0;e<64;++e){ float ov=o[e]; so += ov*fc_w[e*512+dd]; sg += ov*gate_w[e*512+dd]; }
        float gate = sigf(sg);
        float hxn  = hn_s[i] + gate*tanhf(so);
        float m = maskb[b*8 + nn];
        size_t gi = (size_t)b*4096 + i;
        hx_out[gi] = (m != 0.f) ? hxn : hx[gi];
    }
}

// ----------------------------------------------------------------
extern "C" void kernel_launch(void* const* d_in, const int* in_sizes, int n_in,
                              void* d_out, int out_size, void* d_ws, size_t ws_size,
                              hipStream_t stream)
{
    const float* inp       = (const float*)d_in[0];
    const float* hx        = (const float*)d_in[1];
    const float* cx        = (const float*)d_in[2];
    const float* ia_wq     = (const float*)d_in[3];
    const float* ia_wk     = (const float*)d_in[4];
    const float* ia_wv     = (const float*)d_in[5];
    const float* ia_fc_w   = (const float*)d_in[6];
    const float* ia_fc_b   = (const float*)d_in[7];
    const float* mha_wq    = (const float*)d_in[8];
    const float* mha_wk    = (const float*)d_in[9];
    const float* mha_wv    = (const float*)d_in[10];
    const float* mha_fc_w  = (const float*)d_in[11];
    const float* mha_fc_b  = (const float*)d_in[12];
    const float* mha_gate_w= (const float*)d_in[13];
    const float* mha_gate_b= (const float*)d_in[14];
    const float* w_ih      = (const float*)d_in[15];
    const float* w_hh      = (const float*)d_in[16];
    const float* b_ih      = (const float*)d_in[17];
    const float* b_hh      = (const float*)d_in[18];

    float* hx_out  = (float*)d_out;
    float* cx_out  = hx_out + (size_t)B_*NHID_;
    float* mask_out= cx_out + (size_t)B_*NHID_;

    // workspace layout
    bf16* wT    = (bf16*)d_ws;                          // 8*2048*1024 bf16 = 32 MB
    bf16* hb16  = wT + (size_t)8*2048*1024;             // 1024*4096 bf16 = 8 MB
    bf16* xb16  = hb16 + (size_t)B_*NHID_;              // 8 MB
    float* hnew = (float*)(xb16 + (size_t)B_*NHID_);    // 16 MB
    float* maskb= hnew + (size_t)B_*NHID_;              // 32 KB

    hipLaunchKernelGGL(k_conv_hx, dim3(2048), dim3(256), 0, stream, hx, hb16);
    hipLaunchKernelGGL(k_wtrans,  dim3(32,8,16), dim3(256), 0, stream, w_ih, w_hh, wT);
    hipLaunchKernelGGL(k_attn_in, dim3(1024), dim3(256), 0, stream,
                       inp, hx, ia_wq, ia_wk, ia_wv, ia_fc_w, ia_fc_b,
                       xb16, maskb, mask_out);
    hipLaunchKernelGGL(k_lstm, dim3(16,8,8), dim3(256), 0, stream,
                       xb16, hb16, wT, b_ih, b_hh, cx, maskb, cx_out, hnew);
    hipLaunchKernelGGL(k_mha_out, dim3(1024), dim3(256), 0, stream,
                       hnew, hx, mha_wq, mha_wk, mha_wv, mha_fc_w, mha_fc_b,
                       mha_gate_w, mha_gate_b, maskb, hx_out);
}

// Round 2
// 468.172 us; speedup vs baseline: 1.2556x; 1.2556x over previous
//
#include <hip/hip_runtime.h>
#include <hip/hip_bf16.h>

#define B_    1024
#define NHID_ 4096
#define NBO   8
#define BSO   512
#define DK_   64

typedef __bf16 bf16;
typedef __bf16 bf16x2 __attribute__((ext_vector_type(2)));
typedef __bf16 bf16x4 __attribute__((ext_vector_type(4)));
typedef __bf16 bf16x8 __attribute__((ext_vector_type(8)));
typedef float  f32x4  __attribute__((ext_vector_type(4)));

__device__ __forceinline__ float sigf(float x){ return 1.0f/(1.0f + __expf(-x)); }

// ---------------------------------------------------------------- hx -> bf16
__global__ __launch_bounds__(256) void k_conv_hx(const float* __restrict__ hx,
                                                 bf16* __restrict__ hb16)
{
    int i = blockIdx.x*blockDim.x + threadIdx.x;
    int stride = gridDim.x*blockDim.x;
    const float4* in4 = (const float4*)hx;
    for (int idx = i; idx < (B_*NHID_/4); idx += stride){
        float4 v = in4[idx];
        bf16x4 o; o.x=(bf16)v.x; o.y=(bf16)v.y; o.z=(bf16)v.z; o.w=(bf16)v.w;
        *(bf16x4*)&hb16[(size_t)idx*4] = o;
    }
}

// ------------------------------------- w_ih/w_hh -> bf16, transposed [n][col][k]
__global__ __launch_bounds__(256) void k_wtrans(const float* __restrict__ w_ih,
                                                const float* __restrict__ w_hh,
                                                bf16* __restrict__ wT)
{
    int n = blockIdx.z >> 1, which = blockIdx.z & 1;
    int k0 = blockIdx.y * 64, c0 = blockIdx.x * 64;
    const float* src = (which ? w_hh : w_ih) + (size_t)n*512*2048;
    __shared__ float tile[64][65];
    int t = threadIdx.x;
    for (int i = t; i < 4096; i += 256){
        int r = i >> 6, c = i & 63;
        tile[r][c] = src[(size_t)(k0+r)*2048 + (c0+c)];
    }
    __syncthreads();
    for (int i = t; i < 4096; i += 256){
        int c = i >> 6, r = i & 63;
        wT[((size_t)n*2048 + (c0+c))*1024 + which*512 + k0 + r] = (bf16)tile[r][c];
    }
}

// ------------------------------------- generic (8,512,64) fp32 -> bf16 transpose
// src[n][k][e] -> dst[(n*colsPerN + colOff + e)*512 + k]
__global__ __launch_bounds__(256) void k_tr(const float* __restrict__ src,
                                            bf16* __restrict__ dst,
                                            int colOff, int colsPerN)
{
    int n = blockIdx.y, k0 = blockIdx.x * 64;
    __shared__ float tile[64][65];
    int t = threadIdx.x;
    const float* s = src + ((size_t)n*512 + k0)*64;
    for (int i=t;i<4096;i+=256){ int r=i>>6, c=i&63; tile[r][c] = s[(size_t)r*64+c]; }
    __syncthreads();
    bf16* d = dst + ((size_t)n*colsPerN + colOff)*512 + k0;
    for (int i=t;i<4096;i+=256){ int c=i>>6, r=i&63; d[(size_t)c*512 + r] = (bf16)tile[r][c]; }
}

// ---------------------------------------------------------------- input attention + mask
// q projection stays fp32: the top-4 threshold (thr-0.01 strict compare) is
// discontinuous — bf16 score error could flip mask bits vs the np reference.
__global__ __launch_bounds__(256) void k_attn_in(
    const float* __restrict__ inp, const float* __restrict__ hx,
    const float* __restrict__ ia_wq, const float* __restrict__ ia_wk,
    const float* __restrict__ ia_wv, const float* __restrict__ ia_fc_w,
    const float* __restrict__ ia_fc_b,
    bf16* __restrict__ xb16, float* __restrict__ maskb, float* __restrict__ mask_out)
{
    int b = blockIdx.x, t = threadIdx.x;
    __shared__ float x_s[512];
    __shared__ float hb_s[4096];
    __shared__ float q_s[512];
    __shared__ float k_s[320];
    __shared__ float v_s[320];
    __shared__ float attn_s[40];
    __shared__ float score_s[8];
    __shared__ float mb_s[8];
    __shared__ float o_s[512];

    for (int i=t;i<512;i+=256) x_s[i] = inp[(size_t)b*512+i];
    const float4* h4 = (const float4*)(hx + (size_t)b*4096);
    for (int i=t;i<1024;i+=256) ((float4*)hb_s)[i] = h4[i];
    __syncthreads();

    for (int i=t;i<512;i+=256){
        int nn=i>>6, e=i&63;
        const float* w = ia_wq + (size_t)nn*512*64 + e;
        const float* h = hb_s + nn*512;
        float s0=0.f,s1=0.f,s2=0.f,s3=0.f;
        for (int d=0; d<512; d+=4){
            s0 += h[d+0]*w[(size_t)(d+0)*64];
            s1 += h[d+1]*w[(size_t)(d+1)*64];
            s2 += h[d+2]*w[(size_t)(d+2)*64];
            s3 += h[d+3]*w[(size_t)(d+3)*64];
        }
        q_s[i]=(s0+s1)+(s2+s3);
    }
    {
        int nn=t>>6, e=t&63;
        const float* wk = ia_wk + (size_t)nn*128*64 + e;
        const float* wv = ia_wv + (size_t)nn*128*64 + e;
        const float* xx = x_s + nn*128;
        float sk=0.f, sv=0.f;
        for (int d=0; d<128; ++d){ float xv=xx[d]; sk += xv*wk[(size_t)d*64]; sv += xv*wv[(size_t)d*64]; }
        k_s[t]=sk; v_s[t]=sv;
        if (t<64){ k_s[256+t]=0.f; v_s[256+t]=0.f; }
    }
    __syncthreads();
    if (t<40){
        int nn=t/5, j=t%5;
        float s=0.f;
        for (int e=0;e<64;++e) s += q_s[nn*64+e]*k_s[j*64+e];
        attn_s[t] = s*0.125f;
    }
    __syncthreads();
    if (t<8){
        float m=attn_s[t*5];
        for (int j=1;j<5;++j) m=fmaxf(m, attn_s[t*5+j]);
        float ex[5]; float sum=0.f;
        for (int j=0;j<5;++j){ ex[j]=__expf(attn_s[t*5+j]-m); sum+=ex[j]; }
        float inv = 1.f/sum;
        for (int j=0;j<5;++j) attn_s[t*5+j] = ex[j]*inv;
        score_s[t] = ex[0]*inv;
    }
    __syncthreads();
    for (int i=t;i<512;i+=256){
        int nn=i>>6, e=i&63;
        float s=0.f;
        #pragma unroll
        for (int j=0;j<5;++j) s += attn_s[nn*5+j]*v_s[j*64+e];
        o_s[i]=s;
    }
    if (t==0){
        float s[8];
        for (int nn=0;nn<8;++nn) s[nn]=score_s[nn];
        for (int ii=1;ii<8;++ii){ float key=s[ii]; int j=ii-1;
            while(j>=0 && s[j]<key){ s[j+1]=s[j]; --j; } s[j+1]=key; }
        float thr = s[3]-0.01f;
        for (int nn=0;nn<8;++nn) mb_s[nn] = (score_s[nn] > thr) ? 1.0f : 0.0f;
    }
    __syncthreads();
    // FC: each thread owns 2 cols for all 8 blocks (float2 weight loads)
    const float2* fw2 = (const float2*)ia_fc_w;   // [e][256] float2
    float2 fb = ((const float2*)ia_fc_b)[t];
    #pragma unroll 1
    for (int nn=0; nn<8; ++nn){
        float sx=fb.x, sy=fb.y;
        const float* o = o_s + nn*64;
        for (int e=0;e<64;++e){
            float ov=o[e]; float2 w=fw2[(size_t)e*256+t];
            sx += ov*w.x; sy += ov*w.y;
        }
        size_t idx = (size_t)b*4096 + nn*512 + 2*t;
        bf16x2 xo; xo.x=(bf16)sx; xo.y=(bf16)sy;
        *(bf16x2*)&xb16[idx] = xo;
        float m = mb_s[nn];
        float2 mo; mo.x=m; mo.y=m;
        *(float2*)&mask_out[idx] = mo;
    }
    if (t<8) maskb[b*8+t] = mb_s[t];
}

// ---------------------------------------------------------------- LSTM gates MFMA + pointwise
__global__ __launch_bounds__(256) void k_lstm(
    const bf16* __restrict__ xb16, const bf16* __restrict__ hb16,
    const bf16* __restrict__ wT, const float* __restrict__ b_ih,
    const float* __restrict__ b_hh, const float* __restrict__ cx,
    const float* __restrict__ maskb,
    float* __restrict__ cx_out, bf16* __restrict__ hn16)
{
    int n  = blockIdx.z;
    int b0 = blockIdx.x * 64;
    int d0 = blockIdx.y * 64;
    int t  = threadIdx.x;
    int wave = t >> 6, lane = t & 63;
    int quad = lane >> 4, l16 = lane & 15;
    int wm = wave & 1, wd = wave >> 1;

    __shared__ bf16 A_s[64*32];
    __shared__ bf16 W_s[4][64*32];

    f32x4 zero = {0.f,0.f,0.f,0.f};
    f32x4 acc[4][2][2];
    #pragma unroll
    for (int g=0;g<4;++g)
        #pragma unroll
        for(int r=0;r<2;++r)
            #pragma unroll
            for(int c=0;c<2;++c) acc[g][r][c] = zero;

    int arow = t >> 2;
    int aseg = t & 3;
    const bf16* wbase = wT + ((size_t)n*2048 + d0)*1024;

    for (int k0 = 0; k0 < 1024; k0 += 32){
        const bf16* asrc = (k0 < 512)
            ? xb16 + (size_t)(b0+arow)*4096 + n*512 + k0 + aseg*8
            : hb16 + (size_t)(b0+arow)*4096 + n*512 + (k0-512) + aseg*8;
        *(bf16x8*)&A_s[arow*32 + aseg*8] = *(const bf16x8*)asrc;
        #pragma unroll
        for (int g=0; g<4; ++g){
            const bf16* wsrc = wbase + (size_t)(g*512 + arow)*1024 + k0 + aseg*8;
            *(bf16x8*)&W_s[g][arow*32 + aseg*8] = *(const bf16x8*)wsrc;
        }
        __syncthreads();
        bf16x8 a0 = *(const bf16x8*)&A_s[(wm*32      + l16)*32 + quad*8];
        bf16x8 a1 = *(const bf16x8*)&A_s[(wm*32 + 16 + l16)*32 + quad*8];
        #pragma unroll
        for (int g=0; g<4; ++g){
            bf16x8 bb0 = *(const bf16x8*)&W_s[g][(wd*32      + l16)*32 + quad*8];
            bf16x8 bb1 = *(const bf16x8*)&W_s[g][(wd*32 + 16 + l16)*32 + quad*8];
            acc[g][0][0] = __builtin_amdgcn_mfma_f32_16x16x32_bf16(a0, bb0, acc[g][0][0], 0,0,0);
            acc[g][0][1] = __builtin_amdgcn_mfma_f32_16x16x32_bf16(a0, bb1, acc[g][0][1], 0,0,0);
            acc[g][1][0] = __builtin_amdgcn_mfma_f32_16x16x32_bf16(a1, bb0, acc[g][1][0], 0,0,0);
            acc[g][1][1] = __builtin_amdgcn_mfma_f32_16x16x32_bf16(a1, bb1, acc[g][1][1], 0,0,0);
        }
        __syncthreads();
    }

    #pragma unroll
    for (int c=0;c<2;++c){
        int col = wd*32 + c*16 + l16;
        int d   = d0 + col;
        float bi  = b_ih[n*2048 +        d] + b_hh[n*2048 +        d];
        float bff = b_ih[n*2048 +  512 + d] + b_hh[n*2048 +  512 + d];
        float bg  = b_ih[n*2048 + 1024 + d] + b_hh[n*2048 + 1024 + d];
        float bo  = b_ih[n*2048 + 1536 + d] + b_hh[n*2048 + 1536 + d];
        #pragma unroll
        for (int r=0;r<2;++r){
            #pragma unroll
            for (int v=0; v<4; ++v){
                int row = wm*32 + r*16 + quad*4 + v;
                int bb  = b0 + row;
                float gi = acc[0][r][c][v] + bi;
                float gf = acc[1][r][c][v] + bff;
                float gg = acc[2][r][c][v] + bg;
                float go = acc[3][r][c][v] + bo;
                size_t gidx = (size_t)bb*4096 + n*512 + d;
                float cb = cx[gidx];
                float cn = sigf(gf)*cb + sigf(gi)*tanhf(gg);
                float hn = sigf(go)*tanhf(cn);
                float m  = maskb[bb*8+n];
                cx_out[gidx] = (m != 0.f) ? cn : cb;
                hn16[gidx]   = (bf16)hn;
            }
        }
    }
}

// ---------------------------------------------------------------- MFMA projection
// A: (B,4096) bf16, slice n*512.  Wt: [n][NCOL][512] bf16.  out: (B,8,NCOL) fp32.
// NCOL = 64*CT.  grid (16 Mtiles, 8 n), block 256.
template<int CT>
__global__ __launch_bounds__(256) void k_proj(const bf16* __restrict__ Abase,
                                              const bf16* __restrict__ Wt,
                                              float* __restrict__ outp)
{
    const int NCOL = 64*CT;
    int n = blockIdx.y, b0 = blockIdx.x*64;
    int t = threadIdx.x, wave = t>>6, lane = t&63, quad = lane>>4, l16 = lane&15;
    __shared__ bf16 A_s[64*32];
    __shared__ bf16 B_s[64*CT*32];
    f32x4 zero = {0.f,0.f,0.f,0.f};
    f32x4 acc[4][CT];
    #pragma unroll
    for (int r=0;r<4;++r)
        #pragma unroll
        for (int c=0;c<CT;++c) acc[r][c]=zero;

    int arow = t>>2, aseg = t&3;
    const bf16* wbase = Wt + (size_t)n*NCOL*512;

    for (int k0=0; k0<512; k0+=32){
        *(bf16x8*)&A_s[arow*32 + aseg*8] =
            *(const bf16x8*)(Abase + (size_t)(b0+arow)*4096 + n*512 + k0 + aseg*8);
        #pragma unroll
        for (int i=0;i<CT;++i){
            int idx = t + i*256;
            int col = idx>>2, seg = idx&3;
            *(bf16x8*)&B_s[col*32 + seg*8] =
                *(const bf16x8*)(wbase + (size_t)col*512 + k0 + seg*8);
        }
        __syncthreads();
        bf16x8 a[4];
        #pragma unroll
        for (int r=0;r<4;++r) a[r] = *(const bf16x8*)&A_s[(r*16+l16)*32 + quad*8];
        #pragma unroll
        for (int c=0;c<CT;++c){
            bf16x8 bb = *(const bf16x8*)&B_s[((wave*CT+c)*16 + l16)*32 + quad*8];
            #pragma unroll
            for (int r=0;r<4;++r)
                acc[r][c] = __builtin_amdgcn_mfma_f32_16x16x32_bf16(a[r], bb, acc[r][c], 0,0,0);
        }
        __syncthreads();
    }
    #pragma unroll
    for (int c=0;c<CT;++c){
        int col = (wave*CT+c)*16 + l16;
        #pragma unroll
        for (int r=0;r<4;++r){
            #pragma unroll
            for (int v=0;v<4;++v){
                int row = b0 + r*16 + quad*4 + v;
                outp[((size_t)row*NBO + n)*NCOL + col] = acc[r][c][v];
            }
        }
    }
}

// ---------------------------------------------------------------- MHA attention + FC + residual + mask
__global__ __launch_bounds__(256) void k_mha_att_fc(
    const float* __restrict__ qkv,     // (B,8,192): q|k|v
    const bf16* __restrict__ hn16, const float* __restrict__ hx,
    const float* __restrict__ fc_w, const float* __restrict__ fc_b,
    const float* __restrict__ gate_w, const float* __restrict__ gate_b,
    const float* __restrict__ maskb, float* __restrict__ hx_out)
{
    int b = blockIdx.x, t = threadIdx.x;
    __shared__ float qkv_s[8][196];   // pad: 196 % 32 = 4 banks apart per row
    __shared__ float attn_s[64];
    __shared__ float o_s[8*64];

    const float* src = qkv + (size_t)b*1536;
    for (int i=t;i<1536;i+=256){ int nn=i/192, j=i%192; qkv_s[nn][j] = src[i]; }
    __syncthreads();
    if (t<64){
        int nn=t>>3, j=t&7;
        float s=0.f;
        for (int e=0;e<64;++e) s += qkv_s[nn][e]*qkv_s[j][64+e];
        attn_s[t]=s*0.125f;
    }
    __syncthreads();
    if (t<8){
        float m=attn_s[t*8];
        for (int j=1;j<8;++j) m=fmaxf(m,attn_s[t*8+j]);
        float ex[8]; float sum=0.f;
        for (int j=0;j<8;++j){ ex[j]=__expf(attn_s[t*8+j]-m); sum+=ex[j]; }
        float inv=1.f/sum;
        for (int j=0;j<8;++j) attn_s[t*8+j]=ex[j]*inv;
    }
    __syncthreads();
    for (int i=t;i<512;i+=256){
        int nn=i>>6, e=i&63;
        float s=0.f;
        #pragma unroll
        for (int j=0;j<8;++j) s += attn_s[nn*8+j]*qkv_s[j][128+e];
        o_s[i]=s;
    }
    __syncthreads();

    // FC: thread owns 2 cols (float2) of both fc and gate, for all 8 blocks
    const float2* fw2 = (const float2*)fc_w;     // [e][256]
    const float2* gw2 = (const float2*)gate_w;
    float2 fb = ((const float2*)fc_b)[t];
    float2 gb = ((const float2*)gate_b)[t];
    float m8[8];
    #pragma unroll
    for (int nn=0;nn<8;++nn) m8[nn] = maskb[b*8+nn];

    #pragma unroll 1
    for (int nn=0; nn<8; ++nn){
        float fx=fb.x, fy=fb.y, gx=gb.x, gy=gb.y;
        const float* o = o_s + nn*64;
        for (int e=0;e<64;++e){
            float ov=o[e];
            float2 wf=fw2[(size_t)e*256+t];
            float2 wg=gw2[(size_t)e*256+t];
            fx += ov*wf.x; fy += ov*wf.y;
            gx += ov*wg.x; gy += ov*wg.y;
        }
        size_t idx = (size_t)b*4096 + nn*512 + 2*t;
        bf16x2 hn2 = *(const bf16x2*)&hn16[idx];
        float2 hxv = *(const float2*)&hx[idx];
        float hxn0 = (float)hn2.x + sigf(gx)*tanhf(fx);
        float hxn1 = (float)hn2.y + sigf(gy)*tanhf(fy);
        float m = m8[nn];
        float2 outv;
        outv.x = (m != 0.f) ? hxn0 : hxv.x;
        outv.y = (m != 0.f) ? hxn1 : hxv.y;
        *(float2*)&hx_out[idx] = outv;
    }
}

// ----------------------------------------------------------------
extern "C" void kernel_launch(void* const* d_in, const int* in_sizes, int n_in,
                              void* d_out, int out_size, void* d_ws, size_t ws_size,
                              hipStream_t stream)
{
    const float* inp       = (const float*)d_in[0];
    const float* hx        = (const float*)d_in[1];
    const float* cx        = (const float*)d_in[2];
    const float* ia_wq     = (const float*)d_in[3];
    const float* ia_wk     = (const float*)d_in[4];
    const float* ia_wv     = (const float*)d_in[5];
    const float* ia_fc_w   = (const float*)d_in[6];
    const float* ia_fc_b   = (const float*)d_in[7];
    const float* mha_wq    = (const float*)d_in[8];
    const float* mha_wk    = (const float*)d_in[9];
    const float* mha_wv    = (const float*)d_in[10];
    const float* mha_fc_w  = (const float*)d_in[11];
    const float* mha_fc_b  = (const float*)d_in[12];
    const float* mha_gate_w= (const float*)d_in[13];
    const float* mha_gate_b= (const float*)d_in[14];
    const float* w_ih      = (const float*)d_in[15];
    const float* w_hh      = (const float*)d_in[16];
    const float* b_ih      = (const float*)d_in[17];
    const float* b_hh      = (const float*)d_in[18];

    float* hx_out  = (float*)d_out;
    float* cx_out  = hx_out + (size_t)B_*NHID_;
    float* mask_out= cx_out + (size_t)B_*NHID_;

    // workspace layout
    bf16* wT     = (bf16*)d_ws;                         // 32 MB
    bf16* hb16   = wT + (size_t)8*2048*1024;            // 8 MB
    bf16* xb16   = hb16 + (size_t)B_*NHID_;             // 8 MB
    bf16* hn16   = xb16 + (size_t)B_*NHID_;             // 8 MB
    bf16* wqkvT  = hn16 + (size_t)B_*NHID_;             // 8*192*512 bf16 = 1.5 MB
    float* qkv   = (float*)(wqkvT + (size_t)8*192*512); // 1024*8*192 f32 = 6 MB
    float* maskb = qkv + (size_t)B_*NBO*192;            // 32 KB

    hipLaunchKernelGGL(k_conv_hx, dim3(2048), dim3(256), 0, stream, hx, hb16);
    hipLaunchKernelGGL(k_wtrans,  dim3(32,8,16), dim3(256), 0, stream, w_ih, w_hh, wT);
    hipLaunchKernelGGL(k_tr, dim3(8,8), dim3(256), 0, stream, mha_wq, wqkvT,   0, 192);
    hipLaunchKernelGGL(k_tr, dim3(8,8), dim3(256), 0, stream, mha_wk, wqkvT,  64, 192);
    hipLaunchKernelGGL(k_tr, dim3(8,8), dim3(256), 0, stream, mha_wv, wqkvT, 128, 192);
    hipLaunchKernelGGL(k_attn_in, dim3(1024), dim3(256), 0, stream,
                       inp, hx, ia_wq, ia_wk, ia_wv, ia_fc_w, ia_fc_b,
                       xb16, maskb, mask_out);
    hipLaunchKernelGGL(k_lstm, dim3(16,8,8), dim3(256), 0, stream,
                       xb16, hb16, wT, b_ih, b_hh, cx, maskb, cx_out, hn16);
    hipLaunchKernelGGL((k_proj<3>), dim3(16,8), dim3(256), 0, stream, hn16, wqkvT, qkv);
    hipLaunchKernelGGL(k_mha_att_fc, dim3(1024), dim3(256), 0, stream,
                       qkv, hn16, hx, mha_fc_w, mha_fc_b, mha_gate_w, mha_gate_b,
                       maskb, hx_out);
}

// Round 3
// 360.198 us; speedup vs baseline: 1.6319x; 1.2998x over previous
//
#include <hip/hip_runtime.h>
#include <hip/hip_bf16.h>

#define B_    1024
#define NHID_ 4096
#define NBO   8
#define BSO   512
#define DK_   64

typedef __bf16 bf16;
typedef __bf16 bf16x2 __attribute__((ext_vector_type(2)));
typedef __bf16 bf16x4 __attribute__((ext_vector_type(4)));
typedef __bf16 bf16x8 __attribute__((ext_vector_type(8)));
typedef float  f32x4  __attribute__((ext_vector_type(4)));

__device__ __forceinline__ float sigf(float x){ return 1.0f/(1.0f + __expf(-x)); }

// async global->LDS, 16B per lane; lds dest must be wave-uniform base (+lane*16 implicit)
__device__ __forceinline__ void gload16(const void* g, void* lds){
    __builtin_amdgcn_global_load_lds((const __attribute__((address_space(1))) unsigned int*)g,
                                     (__attribute__((address_space(3))) unsigned int*)lds,
                                     16, 0, 0);
}

// ---------------------------------------------------------------- hx -> bf16
__global__ __launch_bounds__(256) void k_conv_hx(const float* __restrict__ hx,
                                                 bf16* __restrict__ hb16)
{
    int i = blockIdx.x*blockDim.x + threadIdx.x;
    int stride = gridDim.x*blockDim.x;
    const float4* in4 = (const float4*)hx;
    for (int idx = i; idx < (B_*NHID_/4); idx += stride){
        float4 v = in4[idx];
        bf16x4 o; o.x=(bf16)v.x; o.y=(bf16)v.y; o.z=(bf16)v.z; o.w=(bf16)v.w;
        *(bf16x4*)&hb16[(size_t)idx*4] = o;
    }
}

// ------------------------------------- w_ih/w_hh -> bf16, transposed [n][col2048][k1024]
__global__ __launch_bounds__(256) void k_wtrans(const float* __restrict__ w_ih,
                                                const float* __restrict__ w_hh,
                                                bf16* __restrict__ wT)
{
    int n = blockIdx.z >> 1, which = blockIdx.z & 1;
    int k0 = blockIdx.y * 64, c0 = blockIdx.x * 64;
    const float* src = (which ? w_hh : w_ih) + (size_t)n*512*2048;
    __shared__ float tile[64][65];
    int t = threadIdx.x;
    for (int i = t; i < 4096; i += 256){
        int r = i >> 6, c = i & 63;
        tile[r][c] = src[(size_t)(k0+r)*2048 + (c0+c)];
    }
    __syncthreads();
    for (int i = t; i < 4096; i += 256){
        int c = i >> 6, r = i & 63;
        wT[((size_t)n*2048 + (c0+c))*1024 + which*512 + k0 + r] = (bf16)tile[r][c];
    }
}

// ------------------------------------- (8,512,64) fp32 -> bf16 transpose (mha qkv weights)
__global__ __launch_bounds__(256) void k_tr(const float* __restrict__ src,
                                            bf16* __restrict__ dst,
                                            int colOff, int colsPerN)
{
    int n = blockIdx.y, k0 = blockIdx.x * 64;
    __shared__ float tile[64][65];
    int t = threadIdx.x;
    const float* s = src + ((size_t)n*512 + k0)*64;
    for (int i=t;i<4096;i+=256){ int r=i>>6, c=i&63; tile[r][c] = s[(size_t)r*64+c]; }
    __syncthreads();
    bf16* d = dst + ((size_t)n*colsPerN + colOff)*512 + k0;
    for (int i=t;i<4096;i+=256){ int c=i>>6, r=i&63; d[(size_t)c*512 + r] = (bf16)tile[r][c]; }
}

// ------------------------------------- small K=64 weight transposes (ia_fc, mha fc|gate paired)
__global__ __launch_bounds__(256) void k_wsmall(const float* __restrict__ ia_fc_w,
                                                const float* __restrict__ fc_w,
                                                const float* __restrict__ gate_w,
                                                bf16* __restrict__ iafcT,
                                                bf16* __restrict__ fcgT)
{
    int idx = blockIdx.x*256 + threadIdx.x;
    if (idx < 512*64){
        int c = idx>>6, k = idx&63;
        iafcT[idx] = (bf16)ia_fc_w[(size_t)k*512 + c];
    }
    int e = idx - 512*64;
    if (e >= 0 && e < 1024*64){
        int cg = e>>6, k = e&63;
        int ct = cg>>6, j = cg&63;
        const float* s = (j<32) ? fc_w : gate_w;
        int col = ct*32 + (j&31);
        fcgT[e] = (bf16)s[(size_t)k*512 + col];
    }
}

// ---------------------------------------------------------------- q = hb @ ia_wq (fp32 exact, tiled)
// grid (32 rowtiles of 32, 8 n), block 256
__global__ __launch_bounds__(256) void k_qgemm(const float* __restrict__ hx,
                                               const float* __restrict__ ia_wq,
                                               float* __restrict__ qbuf)
{
    int b0 = blockIdx.x*32, n = blockIdx.y, t = threadIdx.x;
    __shared__ float A_s[32][20];
    __shared__ float W_s[16][64];
    int tx = t&15, ty = t>>4;
    float acc[2][4] = {{0,0,0,0},{0,0,0,0}};
    for (int k0=0; k0<512; k0+=16){
        if (t < 128){
            int row=t>>2, seg=t&3;
            *(float4*)&A_s[row][seg*4] = *(const float4*)&hx[(size_t)(b0+row)*4096 + n*512 + k0 + seg*4];
        }
        {
            int kk=t>>4, e4=(t&15)*4;
            *(float4*)&W_s[kk][e4] = *(const float4*)&ia_wq[(size_t)n*32768 + (size_t)(k0+kk)*64 + e4];
        }
        __syncthreads();
        #pragma unroll
        for (int kk=0; kk<16; ++kk){
            float a0=A_s[ty*2][kk], a1=A_s[ty*2+1][kk];
            float4 wv=*(float4*)&W_s[kk][tx*4];
            acc[0][0]+=a0*wv.x; acc[0][1]+=a0*wv.y; acc[0][2]+=a0*wv.z; acc[0][3]+=a0*wv.w;
            acc[1][0]+=a1*wv.x; acc[1][1]+=a1*wv.y; acc[1][2]+=a1*wv.z; acc[1][3]+=a1*wv.w;
        }
        __syncthreads();
    }
    #pragma unroll
    for (int r=0;r<2;++r){
        float4 o; o.x=acc[r][0]; o.y=acc[r][1]; o.z=acc[r][2]; o.w=acc[r][3];
        *(float4*)&qbuf[(size_t)(b0+ty*2+r)*512 + n*64 + tx*4] = o;
    }
}

// ---------------------------------------------------------------- k,v = x @ ia_wk/ia_wv (fp32, tiled)
// grid (32 rowtiles of 32, 4 input blocks)
__global__ __launch_bounds__(256) void k_kvgemm(const float* __restrict__ inp,
                                                const float* __restrict__ ia_wk,
                                                const float* __restrict__ ia_wv,
                                                float* __restrict__ kbuf,
                                                float* __restrict__ vbuf)
{
    int b0 = blockIdx.x*32, j = blockIdx.y, t = threadIdx.x;
    __shared__ float A_s[32][20];
    __shared__ float Wk_s[16][64];
    __shared__ float Wv_s[16][64];
    int tx = t&15, ty = t>>4;
    float ak[2][4] = {{0,0,0,0},{0,0,0,0}};
    float av[2][4] = {{0,0,0,0},{0,0,0,0}};
    for (int k0=0; k0<128; k0+=16){
        if (t < 128){
            int row=t>>2, seg=t&3;
            *(float4*)&A_s[row][seg*4] = *(const float4*)&inp[(size_t)(b0+row)*512 + j*128 + k0 + seg*4];
        }
        {
            int kk=t>>4, e4=(t&15)*4;
            *(float4*)&Wk_s[kk][e4] = *(const float4*)&ia_wk[(size_t)j*8192 + (size_t)(k0+kk)*64 + e4];
            *(float4*)&Wv_s[kk][e4] = *(const float4*)&ia_wv[(size_t)j*8192 + (size_t)(k0+kk)*64 + e4];
        }
        __syncthreads();
        #pragma unroll
        for (int kk=0; kk<16; ++kk){
            float a0=A_s[ty*2][kk], a1=A_s[ty*2+1][kk];
            float4 wk=*(float4*)&Wk_s[kk][tx*4];
            float4 wv=*(float4*)&Wv_s[kk][tx*4];
            ak[0][0]+=a0*wk.x; ak[0][1]+=a0*wk.y; ak[0][2]+=a0*wk.z; ak[0][3]+=a0*wk.w;
            ak[1][0]+=a1*wk.x; ak[1][1]+=a1*wk.y; ak[1][2]+=a1*wk.z; ak[1][3]+=a1*wk.w;
            av[0][0]+=a0*wv.x; av[0][1]+=a0*wv.y; av[0][2]+=a0*wv.z; av[0][3]+=a0*wv.w;
            av[1][0]+=a1*wv.x; av[1][1]+=a1*wv.y; av[1][2]+=a1*wv.z; av[1][3]+=a1*wv.w;
        }
        __syncthreads();
    }
    #pragma unroll
    for (int r=0;r<2;++r){
        float4 ok; ok.x=ak[r][0]; ok.y=ak[r][1]; ok.z=ak[r][2]; ok.w=ak[r][3];
        float4 ov; ov.x=av[r][0]; ov.y=av[r][1]; ov.z=av[r][2]; ov.w=av[r][3];
        *(float4*)&kbuf[(size_t)(b0+ty*2+r)*256 + j*64 + tx*4] = ok;
        *(float4*)&vbuf[(size_t)(b0+ty*2+r)*256 + j*64 + tx*4] = ov;
    }
}

// ---------------------------------------------------------------- scores + softmax + top4 + o (ia attention)
// 4 b per block (64 threads each), grid 256
__global__ __launch_bounds__(256) void k_score(const float* __restrict__ qbuf,
                                               const float* __restrict__ kbuf,
                                               const float* __restrict__ vbuf,
                                               bf16* __restrict__ obuf,
                                               float* __restrict__ maskb,
                                               float* __restrict__ mask_out)
{
    int t = threadIdx.x, sb = t>>6, ts = t&63;
    int b = blockIdx.x*4 + sb;
    __shared__ float q_s[4][512];
    __shared__ float k_s[4][256];
    __shared__ float v_s[4][256];
    __shared__ float at_s[4][40];
    __shared__ float sc_s[4][8];
    __shared__ float mb_s[4][8];

    #pragma unroll
    for (int r=0;r<8;++r) q_s[sb][ts+r*64] = qbuf[(size_t)b*512 + ts + r*64];
    #pragma unroll
    for (int r=0;r<4;++r){
        k_s[sb][ts+r*64] = kbuf[(size_t)b*256 + ts + r*64];
        v_s[sb][ts+r*64] = vbuf[(size_t)b*256 + ts + r*64];
    }
    __syncthreads();
    if (ts < 40){
        int n = ts/5, j = ts%5;
        float s = 0.f;
        if (j < 4){
            const float* q = &q_s[sb][n*64];
            const float* k = &k_s[sb][j*64];
            for (int e=0;e<64;++e) s += q[e]*k[e];
            s *= 0.125f;
        }
        at_s[sb][ts] = s;   // j==4: zero logit (appended zero block)
    }
    __syncthreads();
    if (ts < 8){
        float m = at_s[sb][ts*5];
        for (int j=1;j<5;++j) m = fmaxf(m, at_s[sb][ts*5+j]);
        float ex[5]; float sum=0.f;
        for (int j=0;j<5;++j){ ex[j]=__expf(at_s[sb][ts*5+j]-m); sum+=ex[j]; }
        float inv = 1.f/sum;
        for (int j=0;j<5;++j) at_s[sb][ts*5+j] = ex[j]*inv;
        sc_s[sb][ts] = ex[0]*inv;
    }
    __syncthreads();
    if (ts == 0){
        float s[8];
        for (int nn=0;nn<8;++nn) s[nn] = sc_s[sb][nn];
        for (int ii=1;ii<8;++ii){ float key=s[ii]; int jj=ii-1;
            while(jj>=0 && s[jj]<key){ s[jj+1]=s[jj]; --jj; } s[jj+1]=key; }
        float thr = s[3]-0.01f;
        for (int nn=0;nn<8;++nn) mb_s[sb][nn] = (sc_s[sb][nn] > thr) ? 1.0f : 0.0f;
    }
    __syncthreads();
    #pragma unroll
    for (int r=0;r<8;++r){
        int i = ts + r*64;
        int n = i>>6, e = i&63;
        float s = 0.f;
        #pragma unroll
        for (int j=0;j<4;++j) s += at_s[sb][n*5+j]*v_s[sb][j*64+e];
        obuf[(size_t)b*512 + i] = (bf16)s;
    }
    if (ts < 8) maskb[b*8+ts] = mb_s[sb][ts];
    float4* mo = (float4*)(mask_out + (size_t)b*4096);
    #pragma unroll
    for (int r=0;r<16;++r){
        int i4 = ts + r*64;
        float m = mb_s[sb][i4>>7];
        float4 mv; mv.x=m; mv.y=m; mv.z=m; mv.w=m;
        mo[i4] = mv;
    }
}

// ---------------------------------------------------------------- xb = o @ ia_fc_w + b (MFMA, K=64)
// grid (128 Mtiles of 64 rows over (b,n)=8192, 8 coltiles of 64)
__global__ __launch_bounds__(256) void k_fc_ia(const bf16* __restrict__ obuf,
                                               const bf16* __restrict__ iafcT,
                                               const float* __restrict__ ia_fc_b,
                                               bf16* __restrict__ xb16)
{
    int bx = blockIdx.x, by = blockIdx.y;
    int t = threadIdx.x, w = t>>6, l = t&63, quad = l>>4, l16 = l&15;
    int wm = w&1, wd = w>>1;
    __shared__ bf16 A_s[64*72];
    __shared__ bf16 W_s[64*72];
    #pragma unroll
    for (int j=0;j<2;++j){
        int c = t + j*256;
        int row = c>>3, seg = c&7;
        *(bf16x8*)&A_s[row*72 + seg*8] = *(const bf16x8*)&obuf[((size_t)bx*64+row)*64 + seg*8];
        *(bf16x8*)&W_s[row*72 + seg*8] = *(const bf16x8*)&iafcT[((size_t)by*64+row)*64 + seg*8];
    }
    __syncthreads();
    f32x4 zero = {0.f,0.f,0.f,0.f};
    f32x4 acc[2][2] = {{zero,zero},{zero,zero}};
    #pragma unroll
    for (int k0=0;k0<64;k0+=32){
        bf16x8 a[2], bb[2];
        #pragma unroll
        for (int r=0;r<2;++r) a[r] = *(const bf16x8*)&A_s[(wm*32+r*16+l16)*72 + k0 + quad*8];
        #pragma unroll
        for (int c=0;c<2;++c) bb[c] = *(const bf16x8*)&W_s[(wd*32+c*16+l16)*72 + k0 + quad*8];
        #pragma unroll
        for (int r=0;r<2;++r)
            #pragma unroll
            for (int c=0;c<2;++c)
                acc[r][c] = __builtin_amdgcn_mfma_f32_16x16x32_bf16(a[r], bb[c], acc[r][c], 0,0,0);
    }
    #pragma unroll
    for (int c=0;c<2;++c){
        int col = by*64 + wd*32 + c*16 + l16;
        float bias = ia_fc_b[col];
        #pragma unroll
        for (int r=0;r<2;++r)
            #pragma unroll
            for (int v=0;v<4;++v){
                int row = bx*64 + wm*32 + r*16 + quad*4 + v;
                xb16[(size_t)row*512 + col] = (bf16)(acc[r][c][v] + bias);
            }
    }
}

// ---------------------------------------------------------------- LSTM gates MFMA + pointwise (v2)
// 128 rows x (4 gates x 64 cols), global_load_lds staging, swizzled LDS, XCD-affine decode.
// grid 512 (bid&7 = n so each XCD keeps one n's A-slice + weights in L2)
__global__ __launch_bounds__(256,2) void k_lstm(
    const bf16* __restrict__ xb16, const bf16* __restrict__ hb16,
    const bf16* __restrict__ wT, const float* __restrict__ b_ih,
    const float* __restrict__ b_hh, const float* __restrict__ cx,
    const float* __restrict__ maskb,
    float* __restrict__ cx_out, bf16* __restrict__ hn16)
{
    int bid = blockIdx.x;
    int n = bid & 7;
    int i = bid >> 3;
    int d0 = (i & 7) * 64;
    int b0 = (i >> 3) * 128;
    int t = threadIdx.x;
    int w = t >> 6, l = t & 63;
    int quad = l >> 4, l16 = l & 15;
    int wm = w & 1, wd = w >> 1;

    __shared__ bf16 A_s[512*8];    // 128 rows x 32 k, chunk-swizzled
    __shared__ bf16 W_s[1024*8];   // 256 cols x 32 k, chunk-swizzled

    f32x4 zero = {0.f,0.f,0.f,0.f};
    f32x4 acc[4][8];
    #pragma unroll
    for (int rf=0;rf<4;++rf)
        #pragma unroll
        for (int cf=0;cf<8;++cf) acc[rf][cf] = zero;

    const bf16* wbase = wT + ((size_t)n*2048 + d0)*1024;

    for (int k0 = 0; k0 < 1024; k0 += 32){
        const bf16* ab = (k0 < 512) ? (xb16 + (size_t)n*512 + k0)
                                    : (hb16 + (size_t)n*512 + (k0-512));
        #pragma unroll
        for (int j=0;j<2;++j){
            int slot = w*64 + l + j*256;
            int row = slot>>2, ss = slot&3;
            int seg = ss ^ ((row>>1)&3);
            gload16(ab + (size_t)(b0+row)*4096 + seg*8, &A_s[(size_t)(w*64 + j*256)*8]);
        }
        #pragma unroll
        for (int j=0;j<4;++j){
            int slot = w*64 + l + j*256;
            int gcol = slot>>2, ss = slot&3;
            int seg = ss ^ ((gcol>>1)&3);
            int g = gcol>>6, dl = gcol&63;
            gload16(wbase + (size_t)(g*512 + dl)*1024 + k0 + seg*8, &W_s[(size_t)(w*64 + j*256)*8]);
        }
        __syncthreads();
        bf16x8 a[4];
        #pragma unroll
        for (int rf=0;rf<4;++rf){
            int row = wm*64 + rf*16 + l16;
            int slot = row*4 + (quad ^ ((row>>1)&3));
            a[rf] = *(const bf16x8*)&A_s[slot*8];
        }
        #pragma unroll
        for (int g=0; g<4; ++g)
            #pragma unroll
            for (int cc=0; cc<2; ++cc){
                int gcol = g*64 + wd*32 + cc*16 + l16;
                int slot = gcol*4 + (quad ^ ((gcol>>1)&3));
                bf16x8 bb = *(const bf16x8*)&W_s[slot*8];
                #pragma unroll
                for (int rf=0;rf<4;++rf)
                    acc[rf][g*2+cc] = __builtin_amdgcn_mfma_f32_16x16x32_bf16(a[rf], bb, acc[rf][g*2+cc], 0,0,0);
            }
        __syncthreads();
    }

    #pragma unroll
    for (int cc=0;cc<2;++cc){
        int d = d0 + wd*32 + cc*16 + l16;
        float bi  = b_ih[n*2048 +        d] + b_hh[n*2048 +        d];
        float bff = b_ih[n*2048 +  512 + d] + b_hh[n*2048 +  512 + d];
        float bg  = b_ih[n*2048 + 1024 + d] + b_hh[n*2048 + 1024 + d];
        float bo  = b_ih[n*2048 + 1536 + d] + b_hh[n*2048 + 1536 + d];
        #pragma unroll
        for (int rf=0;rf<4;++rf){
            #pragma unroll
            for (int v=0;v<4;++v){
                int row = b0 + wm*64 + rf*16 + quad*4 + v;
                float gi = acc[rf][0*2+cc][v] + bi;
                float gf = acc[rf][1*2+cc][v] + bff;
                float gg = acc[rf][2*2+cc][v] + bg;
                float go = acc[rf][3*2+cc][v] + bo;
                size_t gidx = (size_t)row*4096 + n*512 + d;
                float cb = cx[gidx];
                float cn = sigf(gf)*cb + sigf(gi)*tanhf(gg);
                float hn = sigf(go)*tanhf(cn);
                float m  = maskb[row*8+n];
                cx_out[gidx] = (m != 0.f) ? cn : cb;
                hn16[gidx]   = (bf16)hn;
            }
        }
    }
}

// ---------------------------------------------------------------- qkv2 = hn @ mha_w{q,k,v} (MFMA)
// grid (16 Mtiles, 8 n, 3 part), 64x64 tile, K=512
__global__ __launch_bounds__(256) void k_proj64(const bf16* __restrict__ hn16,
                                                const bf16* __restrict__ wqkvT,
                                                float* __restrict__ qkv2)
{
    int b0 = blockIdx.x*64, n = blockIdx.y, ct = blockIdx.z;
    int t = threadIdx.x, w = t>>6, l = t&63, quad = l>>4, l16 = l&15;
    int wm = w&1, wd = w>>1;
    __shared__ bf16 A_s[256*8];
    __shared__ bf16 B_s[256*8];
    f32x4 zero = {0.f,0.f,0.f,0.f};
    f32x4 acc[2][2] = {{zero,zero},{zero,zero}};
    const bf16* ab = hn16 + (size_t)n*512;
    const bf16* wb = wqkvT + ((size_t)n*192 + ct*64)*512;

    for (int k0=0;k0<512;k0+=32){
        {
            int slot = t;
            int row = slot>>2, ss = slot&3;
            int seg = ss ^ ((row>>1)&3);
            gload16(ab + (size_t)(b0+row)*4096 + k0 + seg*8, &A_s[(size_t)(w*64)*8]);
            gload16(wb + (size_t)row*512      + k0 + seg*8, &B_s[(size_t)(w*64)*8]);
        }
        __syncthreads();
        bf16x8 a[2], bb[2];
        #pragma unroll
        for (int r=0;r<2;++r){
            int row = wm*32 + r*16 + l16;
            int slot = row*4 + (quad ^ ((row>>1)&3));
            a[r] = *(const bf16x8*)&A_s[slot*8];
        }
        #pragma unroll
        for (int c=0;c<2;++c){
            int col = wd*32 + c*16 + l16;
            int slot = col*4 + (quad ^ ((col>>1)&3));
            bb[c] = *(const bf16x8*)&B_s[slot*8];
        }
        #pragma unroll
        for (int r=0;r<2;++r)
            #pragma unroll
            for (int c=0;c<2;++c)
                acc[r][c] = __builtin_amdgcn_mfma_f32_16x16x32_bf16(a[r], bb[c], acc[r][c], 0,0,0);
        __syncthreads();
    }
    #pragma unroll
    for (int c=0;c<2;++c){
        int col = ct*64 + wd*32 + c*16 + l16;
        #pragma unroll
        for (int r=0;r<2;++r)
            #pragma unroll
            for (int v=0;v<4;++v){
                int row = b0 + wm*32 + r*16 + quad*4 + v;
                qkv2[(size_t)row*1536 + n*192 + col] = acc[r][c][v];
            }
    }
}

// ---------------------------------------------------------------- mha attention (8 keys) -> o2 bf16
__global__ __launch_bounds__(256) void k_att2(const float* __restrict__ qkv2,
                                              bf16* __restrict__ o2buf)
{
    int t = threadIdx.x, sb = t>>6, ts = t&63;
    int b = blockIdx.x*4 + sb;
    __shared__ float q_s[4][512];
    __shared__ float k_s[4][512];
    __shared__ float v_s[4][512];
    __shared__ float at_s[4][64];
    #pragma unroll
    for (int r=0;r<8;++r){
        int i = ts + r*64;
        int n = i>>6, e = i&63;
        const float* src = qkv2 + (size_t)b*1536 + n*192;
        q_s[sb][i] = src[e];
        k_s[sb][i] = src[64+e];
        v_s[sb][i] = src[128+e];
    }
    __syncthreads();
    {
        int n = ts>>3, j = ts&7;
        float s = 0.f;
        const float* q = &q_s[sb][n*64];
        const float* k = &k_s[sb][j*64];
        for (int e=0;e<64;++e) s += q[e]*k[e];
        at_s[sb][ts] = s*0.125f;
    }
    __syncthreads();
    if (ts < 8){
        float m = at_s[sb][ts*8];
        for (int j=1;j<8;++j) m = fmaxf(m, at_s[sb][ts*8+j]);
        float ex[8]; float sum=0.f;
        for (int j=0;j<8;++j){ ex[j]=__expf(at_s[sb][ts*8+j]-m); sum+=ex[j]; }
        float inv = 1.f/sum;
        for (int j=0;j<8;++j) at_s[sb][ts*8+j] = ex[j]*inv;
    }
    __syncthreads();
    #pragma unroll
    for (int r=0;r<8;++r){
        int i = ts + r*64;
        int n = i>>6, e = i&63;
        float s = 0.f;
        #pragma unroll
        for (int j=0;j<8;++j) s += at_s[sb][n*8+j]*v_s[sb][j*64+e];
        o2buf[(size_t)b*512 + i] = (bf16)s;
    }
}

// ---------------------------------------------------------------- hx_out = mask ? hn + sig(gate)*tanh(fc) : hx
// MFMA K=64, paired cols: tile cols 0-31 = fc d, 32-63 = gate d. grid (128 Mtiles, 16 ct)
__global__ __launch_bounds__(256) void k_fcgate(const bf16* __restrict__ o2buf,
                                                const bf16* __restrict__ fcgT,
                                                const float* __restrict__ fc_b,
                                                const float* __restrict__ gate_b,
                                                const bf16* __restrict__ hn16,
                                                const float* __restrict__ hx,
                                                const float* __restrict__ maskb,
                                                float* __restrict__ hx_out)
{
    int bx = blockIdx.x, ct = blockIdx.y;
    int t = threadIdx.x, w = t>>6, l = t&63, quad = l>>4, l16 = l&15;
    __shared__ bf16 A_s[64*72];
    __shared__ bf16 W_s[64*72];
    #pragma unroll
    for (int j=0;j<2;++j){
        int c = t + j*256;
        int row = c>>3, seg = c&7;
        *(bf16x8*)&A_s[row*72 + seg*8] = *(const bf16x8*)&o2buf[((size_t)bx*64+row)*64 + seg*8];
        *(bf16x8*)&W_s[row*72 + seg*8] = *(const bf16x8*)&fcgT[((size_t)ct*64+row)*64 + seg*8];
    }
    __syncthreads();
    f32x4 zero = {0.f,0.f,0.f,0.f};
    f32x4 acc[4] = {zero,zero,zero,zero};
    #pragma unroll
    for (int k0=0;k0<64;k0+=32){
        bf16x8 a = *(const bf16x8*)&A_s[(w*16+l16)*72 + k0 + quad*8];
        #pragma unroll
        for (int c=0;c<4;++c){
            bf16x8 bb = *(const bf16x8*)&W_s[(c*16+l16)*72 + k0 + quad*8];
            acc[c] = __builtin_amdgcn_mfma_f32_16x16x32_bf16(a, bb, acc[c], 0,0,0);
        }
    }
    #pragma unroll
    for (int c=0;c<2;++c){
        int d = ct*32 + c*16 + l16;
        float fb = fc_b[d], gb = gate_b[d];
        #pragma unroll
        for (int v=0;v<4;++v){
            int row = bx*64 + w*16 + quad*4 + v;
            int b = row>>3, n = row&7;
            size_t idx = (size_t)b*4096 + n*512 + d;
            float f = acc[c][v]   + fb;
            float g = acc[c+2][v] + gb;
            float hn = (float)hn16[idx];
            float m = maskb[row];
            hx_out[idx] = (m != 0.f) ? (hn + sigf(g)*tanhf(f)) : hx[idx];
        }
    }
}

// ----------------------------------------------------------------
extern "C" void kernel_launch(void* const* d_in, const int* in_sizes, int n_in,
                              void* d_out, int out_size, void* d_ws, size_t ws_size,
                              hipStream_t stream)
{
    const float* inp       = (const float*)d_in[0];
    const float* hx        = (const float*)d_in[1];
    const float* cx        = (const float*)d_in[2];
    const float* ia_wq     = (const float*)d_in[3];
    const float* ia_wk     = (const float*)d_in[4];
    const float* ia_wv     = (const float*)d_in[5];
    const float* ia_fc_w   = (const float*)d_in[6];
    const float* ia_fc_b   = (const float*)d_in[7];
    const float* mha_wq    = (const float*)d_in[8];
    const float* mha_wk    = (const float*)d_in[9];
    const float* mha_wv    = (const float*)d_in[10];
    const float* mha_fc_w  = (const float*)d_in[11];
    const float* mha_fc_b  = (const float*)d_in[12];
    const float* mha_gate_w= (const float*)d_in[13];
    const float* mha_gate_b= (const float*)d_in[14];
    const float* w_ih      = (const float*)d_in[15];
    const float* w_hh      = (const float*)d_in[16];
    const float* b_ih      = (const float*)d_in[17];
    const float* b_hh      = (const float*)d_in[18];

    float* hx_out  = (float*)d_out;
    float* cx_out  = hx_out + (size_t)B_*NHID_;
    float* mask_out= cx_out + (size_t)B_*NHID_;

    // workspace layout (bytes)
    char* p = (char*)d_ws;
    bf16* wT     = (bf16*)p;               p += (size_t)8*2048*1024*2;   // 32 MB
    bf16* hb16   = (bf16*)p;               p += (size_t)B_*NHID_*2;      // 8 MB
    bf16* xb16   = (bf16*)p;               p += (size_t)B_*NHID_*2;      // 8 MB
    bf16* hn16   = (bf16*)p;               p += (size_t)B_*NHID_*2;      // 8 MB
    bf16* wqkvT  = (bf16*)p;               p += (size_t)8*192*512*2;     // 1.5 MB
    bf16* iafcT  = (bf16*)p;               p += (size_t)512*64*2;        // 64 KB
    bf16* fcgT   = (bf16*)p;               p += (size_t)1024*64*2;       // 128 KB
    float* qbuf  = (float*)p;              p += (size_t)B_*512*4;        // 2 MB
    float* kbuf  = (float*)p;              p += (size_t)B_*256*4;        // 1 MB
    float* vbuf  = (float*)p;              p += (size_t)B_*256*4;        // 1 MB
    bf16* obuf   = (bf16*)p;               p += (size_t)B_*8*64*2;       // 1 MB
    bf16* o2buf  = (bf16*)p;               p += (size_t)B_*8*64*2;       // 1 MB
    float* qkv2  = (float*)p;              p += (size_t)B_*1536*4;       // 6 MB
    float* maskb = (float*)p;              p += (size_t)B_*8*4;          // 32 KB

    hipLaunchKernelGGL(k_conv_hx, dim3(2048), dim3(256), 0, stream, hx, hb16);
    hipLaunchKernelGGL(k_wtrans,  dim3(32,8,16), dim3(256), 0, stream, w_ih, w_hh, wT);
    hipLaunchKernelGGL(k_tr, dim3(8,8), dim3(256), 0, stream, mha_wq, wqkvT,   0, 192);
    hipLaunchKernelGGL(k_tr, dim3(8,8), dim3(256), 0, stream, mha_wk, wqkvT,  64, 192);
    hipLaunchKernelGGL(k_tr, dim3(8,8), dim3(256), 0, stream, mha_wv, wqkvT, 128, 192);
    hipLaunchKernelGGL(k_wsmall, dim3(384), dim3(256), 0, stream,
                       ia_fc_w, mha_fc_w, mha_gate_w, iafcT, fcgT);
    hipLaunchKernelGGL(k_qgemm, dim3(32,8), dim3(256), 0, stream, hx, ia_wq, qbuf);
    hipLaunchKernelGGL(k_kvgemm, dim3(32,4), dim3(256), 0, stream, inp, ia_wk, ia_wv, kbuf, vbuf);
    hipLaunchKernelGGL(k_score, dim3(256), dim3(256), 0, stream,
                       qbuf, kbuf, vbuf, obuf, maskb, mask_out);
    hipLaunchKernelGGL(k_fc_ia, dim3(128,8), dim3(256), 0, stream, obuf, iafcT, ia_fc_b, xb16);
    hipLaunchKernelGGL(k_lstm, dim3(512), dim3(256), 0, stream,
                       xb16, hb16, wT, b_ih, b_hh, cx, maskb, cx_out, hn16);
    hipLaunchKernelGGL(k_proj64, dim3(16,8,3), dim3(256), 0, stream, hn16, wqkvT, qkv2);
    hipLaunchKernelGGL(k_att2, dim3(256), dim3(256), 0, stream, qkv2, o2buf);
    hipLaunchKernelGGL(k_fcgate, dim3(128,16), dim3(256), 0, stream,
                       o2buf, fcgT, mha_fc_b, mha_gate_b, hn16, hx, maskb, hx_out);
}

// Round 4
// 317.668 us; speedup vs baseline: 1.8504x; 1.1339x over previous
//
#include <hip/hip_runtime.h>
#include <hip/hip_bf16.h>

#define B_    1024
#define NHID_ 4096
#define NBO   8
#define BSO   512
#define DK_   64

typedef __bf16 bf16;
typedef __bf16 bf16x2 __attribute__((ext_vector_type(2)));
typedef __bf16 bf16x4 __attribute__((ext_vector_type(4)));
typedef __bf16 bf16x8 __attribute__((ext_vector_type(8)));
typedef float  f32x4  __attribute__((ext_vector_type(4)));

__device__ __forceinline__ float sigf(float x){ return 1.0f/(1.0f + __expf(-x)); }

// async global->LDS, 16B per lane; lds dest is wave-uniform base (+lane*16 implicit)
__device__ __forceinline__ void gload16(const void* g, void* lds){
    __builtin_amdgcn_global_load_lds((const __attribute__((address_space(1))) unsigned int*)g,
                                     (__attribute__((address_space(3))) unsigned int*)lds,
                                     16, 0, 0);
}

// ---------------------------------------------------------------- fused prep:
// hx->bf16, mha qkv weight transpose->bf16, ia_fc transpose, mha fc|gate paired transpose
__global__ __launch_bounds__(256) void k_prep(
    const float* __restrict__ hx,
    const float* __restrict__ mha_wq, const float* __restrict__ mha_wk,
    const float* __restrict__ mha_wv, const float* __restrict__ ia_fc_w,
    const float* __restrict__ fc_w, const float* __restrict__ gate_w,
    bf16* __restrict__ hb16, bf16* __restrict__ wqkvT,
    bf16* __restrict__ iafcT, bf16* __restrict__ fcgT)
{
    int gid = blockIdx.x*256 + threadIdx.x;
    if (gid < 1048576){
        float4 v = ((const float4*)hx)[gid];
        bf16x4 o; o.x=(bf16)v.x; o.y=(bf16)v.y; o.z=(bf16)v.z; o.w=(bf16)v.w;
        *(bf16x4*)&hb16[(size_t)gid*4] = o;
        return;
    }
    int e = gid - 1048576;
    if (e < 786432){   // wqkvT[(n*192+c)*512 + k] = w[p][n][k][ee]
        int col = e >> 9, k = e & 511;
        int n = col / 192, c = col - n*192;
        int p = c >> 6, ee = c & 63;
        const float* s = (p==0) ? mha_wq : ((p==1) ? mha_wk : mha_wv);
        wqkvT[e] = (bf16)s[((size_t)n*512 + k)*64 + ee];
        return;
    }
    e -= 786432;
    if (e < 32768){    // iafcT[c*64+k] = ia_fc_w[k*512+c]
        int c = e>>6, k = e&63;
        iafcT[e] = (bf16)ia_fc_w[(size_t)k*512 + c];
        return;
    }
    e -= 32768;
    if (e < 65536){    // fcgT: 16 tiles of 64 cols: cols 0-31 fc, 32-63 gate
        int cg = e>>6, k = e&63;
        int ct = cg>>6, j = cg&63;
        const float* s = (j<32) ? fc_w : gate_w;
        int col = ct*32 + (j&31);
        fcgT[e] = (bf16)s[(size_t)k*512 + col];
    }
}

// ------------------------------------- w_ih/w_hh -> bf16, transposed [n][gcol2048][k1024]
__global__ __launch_bounds__(256) void k_wtrans(const float* __restrict__ w_ih,
                                                const float* __restrict__ w_hh,
                                                bf16* __restrict__ wT)
{
    int n = blockIdx.z >> 1, which = blockIdx.z & 1;
    int k0 = blockIdx.y * 64, c0 = blockIdx.x * 64;
    const float* src = (which ? w_hh : w_ih) + (size_t)n*512*2048;
    __shared__ float tile[64][65];
    int t = threadIdx.x;
    #pragma unroll
    for (int it=0; it<4; ++it){
        int idx = t + it*256;
        int r = idx>>4, c4 = (idx&15)*4;
        *(float4*)&tile[r][c4] = *(const float4*)&src[(size_t)(k0+r)*2048 + c0 + c4];
    }
    __syncthreads();
    #pragma unroll
    for (int it=0; it<2; ++it){
        int idx = t + it*256;
        int c = idx>>3, r8 = (idx&7)*8;
        bf16x8 v;
        #pragma unroll
        for (int jj=0;jj<8;++jj) v[jj] = (bf16)tile[r8+jj][c];
        *(bf16x8*)&wT[((size_t)n*2048 + c0 + c)*1024 + which*512 + k0 + r8] = v;
    }
}

// ---------------------------------------------------------------- q / k / v input-attn GEMMs (fp32 exact)
// grid (16 Mtiles of 64 rows, 12): y<8 -> q for n=y; else kv for j=y-8
__global__ __launch_bounds__(256) void k_qkv(const float* __restrict__ hx,
                                             const float* __restrict__ inp,
                                             const float* __restrict__ ia_wq,
                                             const float* __restrict__ ia_wk,
                                             const float* __restrict__ ia_wv,
                                             float* __restrict__ qbuf,
                                             float* __restrict__ kbuf,
                                             float* __restrict__ vbuf)
{
    int b0 = blockIdx.x*64, y = blockIdx.y, t = threadIdx.x;
    int tx = t&15, ty = t>>4;
    __shared__ float A_s[64][20];
    __shared__ float W1_s[16][68];
    __shared__ float W2_s[16][68];
    if (y < 8){
        int n = y;
        float acc[4][4] = {};
        for (int k0=0; k0<512; k0+=16){
            { int row=t>>2, seg=(t&3)*4;
              *(float4*)&A_s[row][seg] = *(const float4*)&hx[(size_t)(b0+row)*4096 + n*512 + k0 + seg]; }
            { int kk=t>>4, e4=(t&15)*4;
              *(float4*)&W1_s[kk][e4] = *(const float4*)&ia_wq[(size_t)n*32768 + (size_t)(k0+kk)*64 + e4]; }
            __syncthreads();
            #pragma unroll
            for (int kk=0; kk<16; ++kk){
                float4 wv = *(float4*)&W1_s[kk][tx*4];
                #pragma unroll
                for (int r=0;r<4;++r){
                    float a = A_s[ty*4+r][kk];
                    acc[r][0]+=a*wv.x; acc[r][1]+=a*wv.y; acc[r][2]+=a*wv.z; acc[r][3]+=a*wv.w;
                }
            }
            __syncthreads();
        }
        #pragma unroll
        for (int r=0;r<4;++r){
            float4 o; o.x=acc[r][0]; o.y=acc[r][1]; o.z=acc[r][2]; o.w=acc[r][3];
            *(float4*)&qbuf[(size_t)(b0+ty*4+r)*512 + n*64 + tx*4] = o;
        }
    } else {
        int j = y-8;
        float ak[4][4] = {}, av[4][4] = {};
        for (int k0=0; k0<128; k0+=16){
            { int row=t>>2, seg=(t&3)*4;
              *(float4*)&A_s[row][seg] = *(const float4*)&inp[(size_t)(b0+row)*512 + j*128 + k0 + seg]; }
            { int kk=t>>4, e4=(t&15)*4;
              *(float4*)&W1_s[kk][e4] = *(const float4*)&ia_wk[(size_t)j*8192 + (size_t)(k0+kk)*64 + e4];
              *(float4*)&W2_s[kk][e4] = *(const float4*)&ia_wv[(size_t)j*8192 + (size_t)(k0+kk)*64 + e4]; }
            __syncthreads();
            #pragma unroll
            for (int kk=0; kk<16; ++kk){
                float4 wk = *(float4*)&W1_s[kk][tx*4];
                float4 wv = *(float4*)&W2_s[kk][tx*4];
                #pragma unroll
                for (int r=0;r<4;++r){
                    float a = A_s[ty*4+r][kk];
                    ak[r][0]+=a*wk.x; ak[r][1]+=a*wk.y; ak[r][2]+=a*wk.z; ak[r][3]+=a*wk.w;
                    av[r][0]+=a*wv.x; av[r][1]+=a*wv.y; av[r][2]+=a*wv.z; av[r][3]+=a*wv.w;
                }
            }
            __syncthreads();
        }
        #pragma unroll
        for (int r=0;r<4;++r){
            float4 ok; ok.x=ak[r][0]; ok.y=ak[r][1]; ok.z=ak[r][2]; ok.w=ak[r][3];
            float4 ov; ov.x=av[r][0]; ov.y=av[r][1]; ov.z=av[r][2]; ov.w=av[r][3];
            *(float4*)&kbuf[(size_t)(b0+ty*4+r)*256 + j*64 + tx*4] = ok;
            *(float4*)&vbuf[(size_t)(b0+ty*4+r)*256 + j*64 + tx*4] = ov;
        }
    }
}

// ---------------------------------------------------------------- scores + softmax + top4 + o
__global__ __launch_bounds__(256) void k_score(const float* __restrict__ qbuf,
                                               const float* __restrict__ kbuf,
                                               const float* __restrict__ vbuf,
                                               bf16* __restrict__ obuf,
                                               float* __restrict__ maskb,
                                               float* __restrict__ mask_out)
{
    int t = threadIdx.x, sb = t>>6, ts = t&63;
    int b = blockIdx.x*4 + sb;
    __shared__ float q_s[4][512];
    __shared__ float k_s[4][256];
    __shared__ float v_s[4][256];
    __shared__ float at_s[4][40];
    __shared__ float sc_s[4][8];
    __shared__ float mb_s[4][8];

    #pragma unroll
    for (int r=0;r<8;++r) q_s[sb][ts+r*64] = qbuf[(size_t)b*512 + ts + r*64];
    #pragma unroll
    for (int r=0;r<4;++r){
        k_s[sb][ts+r*64] = kbuf[(size_t)b*256 + ts + r*64];
        v_s[sb][ts+r*64] = vbuf[(size_t)b*256 + ts + r*64];
    }
    __syncthreads();
    if (ts < 40){
        int n = ts/5, j = ts%5;
        float s = 0.f;
        if (j < 4){
            const float* q = &q_s[sb][n*64];
            const float* k = &k_s[sb][j*64];
            for (int e=0;e<64;++e) s += q[e]*k[e];
            s *= 0.125f;
        }
        at_s[sb][ts] = s;
    }
    __syncthreads();
    if (ts < 8){
        float m = at_s[sb][ts*5];
        for (int j=1;j<5;++j) m = fmaxf(m, at_s[sb][ts*5+j]);
        float ex[5]; float sum=0.f;
        for (int j=0;j<5;++j){ ex[j]=__expf(at_s[sb][ts*5+j]-m); sum+=ex[j]; }
        float inv = 1.f/sum;
        for (int j=0;j<5;++j) at_s[sb][ts*5+j] = ex[j]*inv;
        sc_s[sb][ts] = ex[0]*inv;
    }
    __syncthreads();
    if (ts == 0){
        float s[8];
        for (int nn=0;nn<8;++nn) s[nn] = sc_s[sb][nn];
        for (int ii=1;ii<8;++ii){ float key=s[ii]; int jj=ii-1;
            while(jj>=0 && s[jj]<key){ s[jj+1]=s[jj]; --jj; } s[jj+1]=key; }
        float thr = s[3]-0.01f;
        for (int nn=0;nn<8;++nn) mb_s[sb][nn] = (sc_s[sb][nn] > thr) ? 1.0f : 0.0f;
    }
    __syncthreads();
    #pragma unroll
    for (int r=0;r<8;++r){
        int i = ts + r*64;
        int n = i>>6, e = i&63;
        float s = 0.f;
        #pragma unroll
        for (int j=0;j<4;++j) s += at_s[sb][n*5+j]*v_s[sb][j*64+e];
        obuf[(size_t)b*512 + i] = (bf16)s;
    }
    if (ts < 8) maskb[b*8+ts] = mb_s[sb][ts];
    float4* mo = (float4*)(mask_out + (size_t)b*4096);
    #pragma unroll
    for (int r=0;r<16;++r){
        int i4 = ts + r*64;
        float m = mb_s[sb][i4>>7];
        float4 mv; mv.x=m; mv.y=m; mv.z=m; mv.w=m;
        mo[i4] = mv;
    }
}

// ---------------------------------------------------------------- xb = o @ ia_fc_w + b (MFMA K=64)
__global__ __launch_bounds__(256) void k_fc_ia(const bf16* __restrict__ obuf,
                                               const bf16* __restrict__ iafcT,
                                               const float* __restrict__ ia_fc_b,
                                               bf16* __restrict__ xb16)
{
    int bx = blockIdx.x, by = blockIdx.y;
    int t = threadIdx.x, w = t>>6, l = t&63, quad = l>>4, l16 = l&15;
    int wm = w&1, wd = w>>1;
    __shared__ bf16 A_s[64*72];
    __shared__ bf16 W_s[64*72];
    #pragma unroll
    for (int j=0;j<2;++j){
        int c = t + j*256;
        int row = c>>3, seg = c&7;
        *(bf16x8*)&A_s[row*72 + seg*8] = *(const bf16x8*)&obuf[((size_t)bx*64+row)*64 + seg*8];
        *(bf16x8*)&W_s[row*72 + seg*8] = *(const bf16x8*)&iafcT[((size_t)by*64+row)*64 + seg*8];
    }
    __syncthreads();
    f32x4 zero = {0.f,0.f,0.f,0.f};
    f32x4 acc[2][2] = {{zero,zero},{zero,zero}};
    #pragma unroll
    for (int k0=0;k0<64;k0+=32){
        bf16x8 a[2], bb[2];
        #pragma unroll
        for (int r=0;r<2;++r) a[r] = *(const bf16x8*)&A_s[(wm*32+r*16+l16)*72 + k0 + quad*8];
        #pragma unroll
        for (int c=0;c<2;++c) bb[c] = *(const bf16x8*)&W_s[(wd*32+c*16+l16)*72 + k0 + quad*8];
        #pragma unroll
        for (int r=0;r<2;++r)
            #pragma unroll
            for (int c=0;c<2;++c)
                acc[r][c] = __builtin_amdgcn_mfma_f32_16x16x32_bf16(a[r], bb[c], acc[r][c], 0,0,0);
    }
    #pragma unroll
    for (int c=0;c<2;++c){
        int col = by*64 + wd*32 + c*16 + l16;
        float bias = ia_fc_b[col];
        #pragma unroll
        for (int r=0;r<2;++r)
            #pragma unroll
            for (int v=0;v<4;++v){
                int row = bx*64 + wm*32 + r*16 + quad*4 + v;
                xb16[(size_t)row*512 + col] = (bf16)(acc[r][c][v] + bias);
            }
    }
}

// ---------------------------------------------------------------- LSTM gates MFMA + pointwise (v3)
// tile: 128 rows x (4 gates x 32 d). grid 1024 (bid&7 = n -> XCD affinity). 4 blocks/CU target.
__global__ __launch_bounds__(256,4) void k_lstm(
    const bf16* __restrict__ xb16, const bf16* __restrict__ hb16,
    const bf16* __restrict__ wT, const float* __restrict__ b_ih,
    const float* __restrict__ b_hh, const float* __restrict__ cx,
    const float* __restrict__ maskb,
    float* __restrict__ cx_out, bf16* __restrict__ hn16)
{
    int bid = blockIdx.x;
    int n = bid & 7;
    int i = bid >> 3;                 // 0..127
    int d0 = (i & 15) * 32;           // 16 d-tiles of 32
    int b0 = (i >> 4) * 128;          // 8 M-tiles of 128
    int t = threadIdx.x;
    int w = t >> 6, l = t & 63;
    int quad = l >> 4, l16 = l & 15;
    int wm = w & 1, wd = w >> 1;

    __shared__ bf16 A_s[512*8];   // 128 rows x 4 segs, chunk-swizzled
    __shared__ bf16 W_s[512*8];   // 128 gate-cols x 4 segs, chunk-swizzled

    f32x4 zero = {0.f,0.f,0.f,0.f};
    f32x4 acc[4][4];              // [rf][gate]
    #pragma unroll
    for (int rf=0;rf<4;++rf)
        #pragma unroll
        for (int g=0;g<4;++g) acc[rf][g] = zero;

    const bf16* wbase = wT + (size_t)n*2048*1024;

    for (int k0 = 0; k0 < 1024; k0 += 32){
        const bf16* ab = (k0 < 512) ? (xb16 + (size_t)n*512 + k0)
                                    : (hb16 + (size_t)n*512 + (k0-512));
        #pragma unroll
        for (int j=0;j<2;++j){
            int slot = j*256 + w*64 + l;
            int row = slot>>2, ss = slot&3;
            int seg = ss ^ ((row>>1)&3);
            gload16(ab + (size_t)(b0+row)*4096 + seg*8, &A_s[(size_t)(j*256 + w*64)*8]);
        }
        #pragma unroll
        for (int j=0;j<2;++j){
            int slot = j*256 + w*64 + l;
            int col = slot>>2, ss = slot&3;
            int seg = ss ^ ((col>>1)&3);
            int g = col>>5, dl = col&31;          // gate, d-local
            gload16(wbase + (size_t)(g*512 + d0 + dl)*1024 + k0 + seg*8,
                    &W_s[(size_t)(j*256 + w*64)*8]);
        }
        __syncthreads();
        bf16x8 a[4];
        #pragma unroll
        for (int rf=0;rf<4;++rf){
            int row = wm*64 + rf*16 + l16;
            int slot = row*4 + (quad ^ ((row>>1)&3));
            a[rf] = *(const bf16x8*)&A_s[slot*8];
        }
        #pragma unroll
        for (int g=0; g<4; ++g){
            int col = g*32 + wd*16 + l16;
            int slot = col*4 + (quad ^ ((col>>1)&3));
            bf16x8 bb = *(const bf16x8*)&W_s[slot*8];
            #pragma unroll
            for (int rf=0;rf<4;++rf)
                acc[rf][g] = __builtin_amdgcn_mfma_f32_16x16x32_bf16(a[rf], bb, acc[rf][g], 0,0,0);
        }
        __syncthreads();
    }

    int d = d0 + wd*16 + l16;
    float bi  = b_ih[n*2048 +        d] + b_hh[n*2048 +        d];
    float bff = b_ih[n*2048 +  512 + d] + b_hh[n*2048 +  512 + d];
    float bg  = b_ih[n*2048 + 1024 + d] + b_hh[n*2048 + 1024 + d];
    float bo  = b_ih[n*2048 + 1536 + d] + b_hh[n*2048 + 1536 + d];
    #pragma unroll
    for (int rf=0;rf<4;++rf){
        #pragma unroll
        for (int v=0;v<4;++v){
            int row = b0 + wm*64 + rf*16 + quad*4 + v;
            float gi = acc[rf][0][v] + bi;
            float gf = acc[rf][1][v] + bff;
            float gg = acc[rf][2][v] + bg;
            float go = acc[rf][3][v] + bo;
            size_t gidx = (size_t)row*4096 + n*512 + d;
            float cb = cx[gidx];
            float cn = sigf(gf)*cb + sigf(gi)*tanhf(gg);
            float hn = sigf(go)*tanhf(cn);
            float m  = maskb[row*8+n];
            cx_out[gidx] = (m != 0.f) ? cn : cb;
            hn16[gidx]   = (bf16)hn;
        }
    }
}

// ---------------------------------------------------------------- qkv2 = hn @ mha_w{q,k,v} (MFMA)
__global__ __launch_bounds__(256) void k_proj64(const bf16* __restrict__ hn16,
                                                const bf16* __restrict__ wqkvT,
                                                float* __restrict__ qkv2)
{
    int b0 = blockIdx.x*64, n = blockIdx.y, ct = blockIdx.z;
    int t = threadIdx.x, w = t>>6, l = t&63, quad = l>>4, l16 = l&15;
    int wm = w&1, wd = w>>1;
    __shared__ bf16 A_s[256*8];
    __shared__ bf16 B_s[256*8];
    f32x4 zero = {0.f,0.f,0.f,0.f};
    f32x4 acc[2][2] = {{zero,zero},{zero,zero}};
    const bf16* ab = hn16 + (size_t)n*512;
    const bf16* wb = wqkvT + ((size_t)n*192 + ct*64)*512;

    for (int k0=0;k0<512;k0+=32){
        {
            int slot = t;
            int row = slot>>2, ss = slot&3;
            int seg = ss ^ ((row>>1)&3);
            gload16(ab + (size_t)(b0+row)*4096 + k0 + seg*8, &A_s[(size_t)(w*64)*8]);
            gload16(wb + (size_t)row*512      + k0 + seg*8, &B_s[(size_t)(w*64)*8]);
        }
        __syncthreads();
        bf16x8 a[2], bb[2];
        #pragma unroll
        for (int r=0;r<2;++r){
            int row = wm*32 + r*16 + l16;
            int slot = row*4 + (quad ^ ((row>>1)&3));
            a[r] = *(const bf16x8*)&A_s[slot*8];
        }
        #pragma unroll
        for (int c=0;c<2;++c){
            int col = wd*32 + c*16 + l16;
            int slot = col*4 + (quad ^ ((col>>1)&3));
            bb[c] = *(const bf16x8*)&B_s[slot*8];
        }
        #pragma unroll
        for (int r=0;r<2;++r)
            #pragma unroll
            for (int c=0;c<2;++c)
                acc[r][c] = __builtin_amdgcn_mfma_f32_16x16x32_bf16(a[r], bb[c], acc[r][c], 0,0,0);
        __syncthreads();
    }
    #pragma unroll
    for (int c=0;c<2;++c){
        int col = ct*64 + wd*32 + c*16 + l16;
        #pragma unroll
        for (int r=0;r<2;++r)
            #pragma unroll
            for (int v=0;v<4;++v){
                int row = b0 + wm*32 + r*16 + quad*4 + v;
                qkv2[(size_t)row*1536 + n*192 + col] = acc[r][c][v];
            }
    }
}

// ---------------------------------------------------------------- mha attention -> o2 bf16
__global__ __launch_bounds__(256) void k_att2(const float* __restrict__ qkv2,
                                              bf16* __restrict__ o2buf)
{
    int t = threadIdx.x, sb = t>>6, ts = t&63;
    int b = blockIdx.x*4 + sb;
    __shared__ float q_s[4][512];
    __shared__ float k_s[4][512];
    __shared__ float v_s[4][512];
    __shared__ float at_s[4][64];
    #pragma unroll
    for (int r=0;r<8;++r){
        int i = ts + r*64;
        int n = i>>6, e = i&63;
        const float* src = qkv2 + (size_t)b*1536 + n*192;
        q_s[sb][i] = src[e];
        k_s[sb][i] = src[64+e];
        v_s[sb][i] = src[128+e];
    }
    __syncthreads();
    {
        int n = ts>>3, j = ts&7;
        float s = 0.f;
        const float* q = &q_s[sb][n*64];
        const float* k = &k_s[sb][j*64];
        for (int e=0;e<64;++e) s += q[e]*k[e];
        at_s[sb][ts] = s*0.125f;
    }
    __syncthreads();
    if (ts < 8){
        float m = at_s[sb][ts*8];
        for (int j=1;j<8;++j) m = fmaxf(m, at_s[sb][ts*8+j]);
        float ex[8]; float sum=0.f;
        for (int j=0;j<8;++j){ ex[j]=__expf(at_s[sb][ts*8+j]-m); sum+=ex[j]; }
        float inv = 1.f/sum;
        for (int j=0;j<8;++j) at_s[sb][ts*8+j] = ex[j]*inv;
    }
    __syncthreads();
    #pragma unroll
    for (int r=0;r<8;++r){
        int i = ts + r*64;
        int n = i>>6, e = i&63;
        float s = 0.f;
        #pragma unroll
        for (int j=0;j<8;++j) s += at_s[sb][n*8+j]*v_s[sb][j*64+e];
        o2buf[(size_t)b*512 + i] = (bf16)s;
    }
}

// ---------------------------------------------------------------- hx_out = mask ? hn + sig(g)*tanh(f) : hx
__global__ __launch_bounds__(256) void k_fcgate(const bf16* __restrict__ o2buf,
                                                const bf16* __restrict__ fcgT,
                                                const float* __restrict__ fc_b,
                                                const float* __restrict__ gate_b,
                                                const bf16* __restrict__ hn16,
                                                const float* __restrict__ hx,
                                                const float* __restrict__ maskb,
                                                float* __restrict__ hx_out)
{
    int bx = blockIdx.x, ct = blockIdx.y;
    int t = threadIdx.x, w = t>>6, l = t&63, quad = l>>4, l16 = l&15;
    __shared__ bf16 A_s[64*72];
    __shared__ bf16 W_s[64*72];
    #pragma unroll
    for (int j=0;j<2;++j){
        int c = t + j*256;
        int row = c>>3, seg = c&7;
        *(bf16x8*)&A_s[row*72 + seg*8] = *(const bf16x8*)&o2buf[((size_t)bx*64+row)*64 + seg*8];
        *(bf16x8*)&W_s[row*72 + seg*8] = *(const bf16x8*)&fcgT[((size_t)ct*64+row)*64 + seg*8];
    }
    __syncthreads();
    f32x4 zero = {0.f,0.f,0.f,0.f};
    f32x4 acc[4] = {zero,zero,zero,zero};
    #pragma unroll
    for (int k0=0;k0<64;k0+=32){
        bf16x8 a = *(const bf16x8*)&A_s[(w*16+l16)*72 + k0 + quad*8];
        #pragma unroll
        for (int c=0;c<4;++c){
            bf16x8 bb = *(const bf16x8*)&W_s[(c*16+l16)*72 + k0 + quad*8];
            acc[c] = __builtin_amdgcn_mfma_f32_16x16x32_bf16(a, bb, acc[c], 0,0,0);
        }
    }
    #pragma unroll
    for (int c=0;c<2;++c){
        int d = ct*32 + c*16 + l16;
        float fb = fc_b[d], gb = gate_b[d];
        #pragma unroll
        for (int v=0;v<4;++v){
            int row = bx*64 + w*16 + quad*4 + v;
            int b = row>>3, n = row&7;
            size_t idx = (size_t)b*4096 + n*512 + d;
            float f = acc[c][v]   + fb;
            float g = acc[c+2][v] + gb;
            float hn = (float)hn16[idx];
            float m = maskb[row];
            hx_out[idx] = (m != 0.f) ? (hn + sigf(g)*tanhf(f)) : hx[idx];
        }
    }
}

// ----------------------------------------------------------------
extern "C" void kernel_launch(void* const* d_in, const int* in_sizes, int n_in,
                              void* d_out, int out_size, void* d_ws, size_t ws_size,
                              hipStream_t stream)
{
    const float* inp       = (const float*)d_in[0];
    const float* hx        = (const float*)d_in[1];
    const float* cx        = (const float*)d_in[2];
    const float* ia_wq     = (const float*)d_in[3];
    const float* ia_wk     = (const float*)d_in[4];
    const float* ia_wv     = (const float*)d_in[5];
    const float* ia_fc_w   = (const float*)d_in[6];
    const float* ia_fc_b   = (const float*)d_in[7];
    const float* mha_wq    = (const float*)d_in[8];
    const float* mha_wk    = (const float*)d_in[9];
    const float* mha_wv    = (const float*)d_in[10];
    const float* mha_fc_w  = (const float*)d_in[11];
    const float* mha_fc_b  = (const float*)d_in[12];
    const float* mha_gate_w= (const float*)d_in[13];
    const float* mha_gate_b= (const float*)d_in[14];
    const float* w_ih      = (const float*)d_in[15];
    const float* w_hh      = (const float*)d_in[16];
    const float* b_ih      = (const float*)d_in[17];
    const float* b_hh      = (const float*)d_in[18];

    float* hx_out  = (float*)d_out;
    float* cx_out  = hx_out + (size_t)B_*NHID_;
    float* mask_out= cx_out + (size_t)B_*NHID_;

    // workspace layout
    char* p = (char*)d_ws;
    bf16* wT     = (bf16*)p;               p += (size_t)8*2048*1024*2;   // 32 MB
    bf16* hb16   = (bf16*)p;               p += (size_t)B_*NHID_*2;      // 8 MB
    bf16* xb16   = (bf16*)p;               p += (size_t)B_*NHID_*2;      // 8 MB
    bf16* hn16   = (bf16*)p;               p += (size_t)B_*NHID_*2;      // 8 MB
    bf16* wqkvT  = (bf16*)p;               p += (size_t)8*192*512*2;     // 1.5 MB
    bf16* iafcT  = (bf16*)p;               p += (size_t)512*64*2;        // 64 KB
    bf16* fcgT   = (bf16*)p;               p += (size_t)1024*64*2;       // 128 KB
    float* qbuf  = (float*)p;              p += (size_t)B_*512*4;        // 2 MB
    float* kbuf  = (float*)p;              p += (size_t)B_*256*4;        // 1 MB
    float* vbuf  = (float*)p;              p += (size_t)B_*256*4;        // 1 MB
    bf16* obuf   = (bf16*)p;               p += (size_t)B_*8*64*2;       // 1 MB
    bf16* o2buf  = (bf16*)p;               p += (size_t)B_*8*64*2;       // 1 MB
    float* qkv2  = (float*)p;              p += (size_t)B_*1536*4;       // 6 MB
    float* maskb = (float*)p;              p += (size_t)B_*8*4;          // 32 KB

    hipLaunchKernelGGL(k_prep, dim3(7552), dim3(256), 0, stream,
                       hx, mha_wq, mha_wk, mha_wv, ia_fc_w, mha_fc_w, mha_gate_w,
                       hb16, wqkvT, iafcT, fcgT);
    hipLaunchKernelGGL(k_wtrans, dim3(32,8,16), dim3(256), 0, stream, w_ih, w_hh, wT);
    hipLaunchKernelGGL(k_qkv, dim3(16,12), dim3(256), 0, stream,
                       hx, inp, ia_wq, ia_wk, ia_wv, qbuf, kbuf, vbuf);
    hipLaunchKernelGGL(k_score, dim3(256), dim3(256), 0, stream,
                       qbuf, kbuf, vbuf, obuf, maskb, mask_out);
    hipLaunchKernelGGL(k_fc_ia, dim3(128,8), dim3(256), 0, stream, obuf, iafcT, ia_fc_b, xb16);
    hipLaunchKernelGGL(k_lstm, dim3(1024), dim3(256), 0, stream,
                       xb16, hb16, wT, b_ih, b_hh, cx, maskb, cx_out, hn16);
    hipLaunchKernelGGL(k_proj64, dim3(16,8,3), dim3(256), 0, stream, hn16, wqkvT, qkv2);
    hipLaunchKernelGGL(k_att2, dim3(256), dim3(256), 0, stream, qkv2, o2buf);
    hipLaunchKernelGGL(k_fcgate, dim3(128,16), dim3(256), 0, stream,
                       o2buf, fcgT, mha_fc_b, mha_gate_b, hn16, hx, maskb, hx_out);
}

// Round 5
// 287.608 us; speedup vs baseline: 2.0438x; 1.1045x over previous
//
#include <hip/hip_runtime.h>
#include <hip/hip_bf16.h>

#define B_    1024
#define NHID_ 4096
#define NBO   8
#define BSO   512
#define DK_   64

typedef __bf16 bf16;
typedef __bf16 bf16x2 __attribute__((ext_vector_type(2)));
typedef __bf16 bf16x4 __attribute__((ext_vector_type(4)));
typedef __bf16 bf16x8 __attribute__((ext_vector_type(8)));
typedef float  f32x4  __attribute__((ext_vector_type(4)));

__device__ __forceinline__ float sigf(float x){
    float e = __expf(-x);
    return __builtin_amdgcn_rcpf(1.0f + e);
}
__device__ __forceinline__ float ftanh(float x){
    float e = __expf(2.0f*x);
    return 1.0f - 2.0f*__builtin_amdgcn_rcpf(e + 1.0f);
}

// async global->LDS, 16B per lane; lds dest is wave-uniform base (+lane*16 implicit)
__device__ __forceinline__ void gload16(const void* g, void* lds){
    __builtin_amdgcn_global_load_lds((const __attribute__((address_space(1))) unsigned int*)g,
                                     (__attribute__((address_space(3))) unsigned int*)lds,
                                     16, 0, 0);
}

// ---------------------------------------------------------------- merged prep:
// blocks < 4096: w_ih/w_hh -> bf16 transposed wT[n][gcol2048][k1024]
// blocks >= 4096: hx->bf16, mha qkv weight transpose, ia_fc transpose, fc|gate paired transpose
__global__ __launch_bounds__(256) void k_prep(
    const float* __restrict__ w_ih, const float* __restrict__ w_hh,
    const float* __restrict__ hx,
    const float* __restrict__ mha_wq, const float* __restrict__ mha_wk,
    const float* __restrict__ mha_wv, const float* __restrict__ ia_fc_w,
    const float* __restrict__ fc_w, const float* __restrict__ gate_w,
    bf16* __restrict__ wT, bf16* __restrict__ hb16, bf16* __restrict__ wqkvT,
    bf16* __restrict__ iafcT, bf16* __restrict__ fcgT)
{
    int bid = blockIdx.x;
    int t = threadIdx.x;
    if (bid < 4096){
        int c0 = (bid & 31)*64;
        int k0 = ((bid>>5)&7)*64;
        int z  = bid>>8;
        int n = z>>1, which = z&1;
        const float* src = (which ? w_hh : w_ih) + (size_t)n*512*2048;
        __shared__ float tile[64][65];
        #pragma unroll
        for (int it=0; it<4; ++it){
            int idx = t + it*256;
            int r = idx>>4, c4 = (idx&15)*4;
            *(float4*)&tile[r][c4] = *(const float4*)&src[(size_t)(k0+r)*2048 + c0 + c4];
        }
        __syncthreads();
        #pragma unroll
        for (int it=0; it<2; ++it){
            int idx = t + it*256;
            int c = idx>>3, r8 = (idx&7)*8;
            bf16x8 v;
            #pragma unroll
            for (int jj=0;jj<8;++jj) v[jj] = (bf16)tile[r8+jj][c];
            *(bf16x8*)&wT[((size_t)n*2048 + c0 + c)*1024 + which*512 + k0 + r8] = v;
        }
        return;
    }
    int gid = (bid-4096)*256 + t;
    if (gid < 1048576){
        float4 v = ((const float4*)hx)[gid];
        bf16x4 o; o.x=(bf16)v.x; o.y=(bf16)v.y; o.z=(bf16)v.z; o.w=(bf16)v.w;
        *(bf16x4*)&hb16[(size_t)gid*4] = o;
        return;
    }
    int e = gid - 1048576;
    if (e < 786432){   // wqkvT[(n*192+c)*512 + k]
        int col = e >> 9, k = e & 511;
        int n = col / 192, c = col - n*192;
        int p = c >> 6, ee = c & 63;
        const float* s = (p==0) ? mha_wq : ((p==1) ? mha_wk : mha_wv);
        wqkvT[e] = (bf16)s[((size_t)n*512 + k)*64 + ee];
        return;
    }
    e -= 786432;
    if (e < 32768){
        int c = e>>6, k = e&63;
        iafcT[e] = (bf16)ia_fc_w[(size_t)k*512 + c];
        return;
    }
    e -= 32768;
    if (e < 65536){
        int cg = e>>6, k = e&63;
        int ct = cg>>6, j = cg&63;
        const float* s = (j<32) ? fc_w : gate_w;
        int col = ct*32 + (j&31);
        fcgT[e] = (bf16)s[(size_t)k*512 + col];
    }
}

// ---------------------------------------------------------------- q / k / v input-attn GEMMs (fp32 exact)
// grid (32 Mtiles of 32 rows, 12): y<8 -> q for n=y; else kv for j=y-8
__global__ __launch_bounds__(256) void k_qkv(const float* __restrict__ hx,
                                             const float* __restrict__ inp,
                                             const float* __restrict__ ia_wq,
                                             const float* __restrict__ ia_wk,
                                             const float* __restrict__ ia_wv,
                                             float* __restrict__ qbuf,
                                             float* __restrict__ kbuf,
                                             float* __restrict__ vbuf)
{
    int b0 = blockIdx.x*32, y = blockIdx.y, t = threadIdx.x;
    int tx = t&15, ty = t>>4;
    __shared__ float Af[32][36];
    __shared__ float W1[32][68];
    __shared__ float W2[32][68];
    if (y < 8){
        int n = y;
        float acc[2][4] = {};
        for (int k0=0; k0<512; k0+=32){
            { int row=t>>3, c4=(t&7)*4;
              *(float4*)&Af[row][c4] = *(const float4*)&hx[(size_t)(b0+row)*4096 + n*512 + k0 + c4]; }
            #pragma unroll
            for (int j=0;j<2;++j){
                int id = j*256 + t;
                int kk = id>>4, e4 = (id&15)*4;
                *(float4*)&W1[kk][e4] = *(const float4*)&ia_wq[(size_t)n*32768 + (size_t)(k0+kk)*64 + e4];
            }
            __syncthreads();
            #pragma unroll
            for (int kk4=0; kk4<8; ++kk4){
                float4 a0 = *(float4*)&Af[ty*2  ][kk4*4];
                float4 a1 = *(float4*)&Af[ty*2+1][kk4*4];
                #pragma unroll
                for (int j=0;j<4;++j){
                    float4 wv = *(float4*)&W1[kk4*4+j][tx*4];
                    float s0 = (j==0)?a0.x:((j==1)?a0.y:((j==2)?a0.z:a0.w));
                    float s1 = (j==0)?a1.x:((j==1)?a1.y:((j==2)?a1.z:a1.w));
                    acc[0][0]+=s0*wv.x; acc[0][1]+=s0*wv.y; acc[0][2]+=s0*wv.z; acc[0][3]+=s0*wv.w;
                    acc[1][0]+=s1*wv.x; acc[1][1]+=s1*wv.y; acc[1][2]+=s1*wv.z; acc[1][3]+=s1*wv.w;
                }
            }
            __syncthreads();
        }
        #pragma unroll
        for (int r=0;r<2;++r){
            float4 o; o.x=acc[r][0]; o.y=acc[r][1]; o.z=acc[r][2]; o.w=acc[r][3];
            *(float4*)&qbuf[(size_t)(b0+ty*2+r)*512 + n*64 + tx*4] = o;
        }
    } else {
        int jb = y-8;
        float ak[2][4] = {}, av[2][4] = {};
        for (int k0=0; k0<128; k0+=32){
            { int row=t>>3, c4=(t&7)*4;
              *(float4*)&Af[row][c4] = *(const float4*)&inp[(size_t)(b0+row)*512 + jb*128 + k0 + c4]; }
            #pragma unroll
            for (int j=0;j<2;++j){
                int id = j*256 + t;
                int kk = id>>4, e4 = (id&15)*4;
                *(float4*)&W1[kk][e4] = *(const float4*)&ia_wk[(size_t)jb*8192 + (size_t)(k0+kk)*64 + e4];
                *(float4*)&W2[kk][e4] = *(const float4*)&ia_wv[(size_t)jb*8192 + (size_t)(k0+kk)*64 + e4];
            }
            __syncthreads();
            #pragma unroll
            for (int kk4=0; kk4<8; ++kk4){
                float4 a0 = *(float4*)&Af[ty*2  ][kk4*4];
                float4 a1 = *(float4*)&Af[ty*2+1][kk4*4];
                #pragma unroll
                for (int j=0;j<4;++j){
                    float4 wk = *(float4*)&W1[kk4*4+j][tx*4];
                    float4 wv = *(float4*)&W2[kk4*4+j][tx*4];
                    float s0 = (j==0)?a0.x:((j==1)?a0.y:((j==2)?a0.z:a0.w));
                    float s1 = (j==0)?a1.x:((j==1)?a1.y:((j==2)?a1.z:a1.w));
                    ak[0][0]+=s0*wk.x; ak[0][1]+=s0*wk.y; ak[0][2]+=s0*wk.z; ak[0][3]+=s0*wk.w;
                    ak[1][0]+=s1*wk.x; ak[1][1]+=s1*wk.y; ak[1][2]+=s1*wk.z; ak[1][3]+=s1*wk.w;
                    av[0][0]+=s0*wv.x; av[0][1]+=s0*wv.y; av[0][2]+=s0*wv.z; av[0][3]+=s0*wv.w;
                    av[1][0]+=s1*wv.x; av[1][1]+=s1*wv.y; av[1][2]+=s1*wv.z; av[1][3]+=s1*wv.w;
                }
            }
            __syncthreads();
        }
        #pragma unroll
        for (int r=0;r<2;++r){
            float4 ok; ok.x=ak[r][0]; ok.y=ak[r][1]; ok.z=ak[r][2]; ok.w=ak[r][3];
            float4 ov; ov.x=av[r][0]; ov.y=av[r][1]; ov.z=av[r][2]; ov.w=av[r][3];
            *(float4*)&kbuf[(size_t)(b0+ty*2+r)*256 + jb*64 + tx*4] = ok;
            *(float4*)&vbuf[(size_t)(b0+ty*2+r)*256 + jb*64 + tx*4] = ov;
        }
    }
}

// ---------------------------------------------------------------- scores + softmax + top4 + o
__global__ __launch_bounds__(256) void k_score(const float* __restrict__ qbuf,
                                               const float* __restrict__ kbuf,
                                               const float* __restrict__ vbuf,
                                               bf16* __restrict__ obuf,
                                               float* __restrict__ maskb,
                                               float* __restrict__ mask_out)
{
    int t = threadIdx.x, sb = t>>6, ts = t&63;
    int b = blockIdx.x*4 + sb;
    __shared__ float q_s[4][512];
    __shared__ float k_s[4][256];
    __shared__ float v_s[4][256];
    __shared__ float at_s[4][40];
    __shared__ float sc_s[4][8];
    __shared__ float mb_s[4][8];

    #pragma unroll
    for (int r=0;r<8;++r) q_s[sb][ts+r*64] = qbuf[(size_t)b*512 + ts + r*64];
    #pragma unroll
    for (int r=0;r<4;++r){
        k_s[sb][ts+r*64] = kbuf[(size_t)b*256 + ts + r*64];
        v_s[sb][ts+r*64] = vbuf[(size_t)b*256 + ts + r*64];
    }
    __syncthreads();
    if (ts < 40){
        int n = ts/5, j = ts%5;
        float s = 0.f;
        if (j < 4){
            const float* q = &q_s[sb][n*64];
            const float* k = &k_s[sb][j*64];
            for (int e=0;e<64;++e) s += q[e]*k[e];
            s *= 0.125f;
        }
        at_s[sb][ts] = s;
    }
    __syncthreads();
    if (ts < 8){
        float m = at_s[sb][ts*5];
        for (int j=1;j<5;++j) m = fmaxf(m, at_s[sb][ts*5+j]);
        float ex[5]; float sum=0.f;
        for (int j=0;j<5;++j){ ex[j]=__expf(at_s[sb][ts*5+j]-m); sum+=ex[j]; }
        float inv = 1.f/sum;
        for (int j=0;j<5;++j) at_s[sb][ts*5+j] = ex[j]*inv;
        sc_s[sb][ts] = ex[0]*inv;
    }
    __syncthreads();
    if (ts == 0){
        float s[8];
        for (int nn=0;nn<8;++nn) s[nn] = sc_s[sb][nn];
        for (int ii=1;ii<8;++ii){ float key=s[ii]; int jj=ii-1;
            while(jj>=0 && s[jj]<key){ s[jj+1]=s[jj]; --jj; } s[jj+1]=key; }
        float thr = s[3]-0.01f;
        for (int nn=0;nn<8;++nn) mb_s[sb][nn] = (sc_s[sb][nn] > thr) ? 1.0f : 0.0f;
    }
    __syncthreads();
    #pragma unroll
    for (int r=0;r<8;++r){
        int i = ts + r*64;
        int n = i>>6, e = i&63;
        float s = 0.f;
        #pragma unroll
        for (int j=0;j<4;++j) s += at_s[sb][n*5+j]*v_s[sb][j*64+e];
        obuf[(size_t)b*512 + i] = (bf16)s;
    }
    if (ts < 8) maskb[b*8+ts] = mb_s[sb][ts];
    float4* mo = (float4*)(mask_out + (size_t)b*4096);
    #pragma unroll
    for (int r=0;r<16;++r){
        int i4 = ts + r*64;
        float m = mb_s[sb][i4>>7];
        float4 mv; mv.x=m; mv.y=m; mv.z=m; mv.w=m;
        mo[i4] = mv;
    }
}

// ---------------------------------------------------------------- xb = o @ ia_fc_w + b (MFMA K=64)
__global__ __launch_bounds__(256) void k_fc_ia(const bf16* __restrict__ obuf,
                                               const bf16* __restrict__ iafcT,
                                               const float* __restrict__ ia_fc_b,
                                               bf16* __restrict__ xb16)
{
    int bx = blockIdx.x, by = blockIdx.y;
    int t = threadIdx.x, w = t>>6, l = t&63, quad = l>>4, l16 = l&15;
    int wm = w&1, wd = w>>1;
    __shared__ bf16 A_s[64*72];
    __shared__ bf16 W_s[64*72];
    #pragma unroll
    for (int j=0;j<2;++j){
        int c = t + j*256;
        int row = c>>3, seg = c&7;
        *(bf16x8*)&A_s[row*72 + seg*8] = *(const bf16x8*)&obuf[((size_t)bx*64+row)*64 + seg*8];
        *(bf16x8*)&W_s[row*72 + seg*8] = *(const bf16x8*)&iafcT[((size_t)by*64+row)*64 + seg*8];
    }
    __syncthreads();
    f32x4 zero = {0.f,0.f,0.f,0.f};
    f32x4 acc[2][2] = {{zero,zero},{zero,zero}};
    #pragma unroll
    for (int k0=0;k0<64;k0+=32){
        bf16x8 a[2], bb[2];
        #pragma unroll
        for (int r=0;r<2;++r) a[r] = *(const bf16x8*)&A_s[(wm*32+r*16+l16)*72 + k0 + quad*8];
        #pragma unroll
        for (int c=0;c<2;++c) bb[c] = *(const bf16x8*)&W_s[(wd*32+c*16+l16)*72 + k0 + quad*8];
        #pragma unroll
        for (int r=0;r<2;++r)
            #pragma unroll
            for (int c=0;c<2;++c)
                acc[r][c] = __builtin_amdgcn_mfma_f32_16x16x32_bf16(a[r], bb[c], acc[r][c], 0,0,0);
    }
    #pragma unroll
    for (int c=0;c<2;++c){
        int col = by*64 + wd*32 + c*16 + l16;
        float bias = ia_fc_b[col];
        #pragma unroll
        for (int r=0;r<2;++r)
            #pragma unroll
            for (int v=0;v<4;++v){
                int row = bx*64 + wm*32 + r*16 + quad*4 + v;
                xb16[(size_t)row*512 + col] = (bf16)(acc[r][c][v] + bias);
            }
    }
}

// ---------------------------------------------------------------- LSTM gates MFMA + pointwise (v4: dbuf)
// tile: 128 rows x (4 gates x 32 d). grid 1024 (bid&7 = n -> XCD affinity).
// Double-buffered LDS: one barrier per K-step; next iter's global_load_lds issued
// right after the barrier so loads are in flight during compute.
__global__ __launch_bounds__(256,4) void k_lstm(
    const bf16* __restrict__ xb16, const bf16* __restrict__ hb16,
    const bf16* __restrict__ wT, const float* __restrict__ b_ih,
    const float* __restrict__ b_hh, const float* __restrict__ cx,
    const float* __restrict__ maskb,
    float* __restrict__ cx_out, bf16* __restrict__ hn16)
{
    int bid = blockIdx.x;
    int n = bid & 7;
    int i = bid >> 3;
    int d0 = (i & 15) * 32;
    int b0 = (i >> 4) * 128;
    int t = threadIdx.x;
    int w = t >> 6, l = t & 63;
    int quad = l >> 4, l16 = l & 15;
    int wm = w & 1, wd = w >> 1;

    __shared__ bf16 A_s[2][512*8];
    __shared__ bf16 W_s[2][512*8];

    f32x4 zero = {0.f,0.f,0.f,0.f};
    f32x4 acc[4][4];
    #pragma unroll
    for (int rf=0;rf<4;++rf)
        #pragma unroll
        for (int g=0;g<4;++g) acc[rf][g] = zero;

    const bf16* wbase = wT + (size_t)n*2048*1024;

    auto stage = [&](int buf, int k0){
        const bf16* ab = (k0 < 512) ? (xb16 + (size_t)n*512 + k0)
                                    : (hb16 + (size_t)n*512 + (k0-512));
        #pragma unroll
        for (int j=0;j<2;++j){
            int slot = j*256 + w*64 + l;
            int row = slot>>2, ss = slot&3;
            int seg = ss ^ ((row>>1)&3);
            gload16(ab + (size_t)(b0+row)*4096 + seg*8, &A_s[buf][(j*256 + w*64)*8]);
        }
        #pragma unroll
        for (int j=0;j<2;++j){
            int slot = j*256 + w*64 + l;
            int col = slot>>2, ss = slot&3;
            int seg = ss ^ ((col>>1)&3);
            int g = col>>5, dl = col&31;
            gload16(wbase + (size_t)(g*512 + d0 + dl)*1024 + k0 + seg*8,
                    &W_s[buf][(j*256 + w*64)*8]);
        }
    };

    stage(0, 0);
    for (int it = 0; it < 32; ++it){
        __syncthreads();                       // buf[it&1] staged; prior reads of buf[it&1^1] done
        if (it < 31) stage((it+1)&1, (it+1)*32);
        int buf = it & 1;
        bf16x8 a[4];
        #pragma unroll
        for (int rf=0;rf<4;++rf){
            int row = wm*64 + rf*16 + l16;
            int slot = row*4 + (quad ^ ((row>>1)&3));
            a[rf] = *(const bf16x8*)&A_s[buf][slot*8];
        }
        #pragma unroll
        for (int g=0; g<4; ++g){
            int col = g*32 + wd*16 + l16;
            int slot = col*4 + (quad ^ ((col>>1)&3));
            bf16x8 bb = *(const bf16x8*)&W_s[buf][slot*8];
            #pragma unroll
            for (int rf=0;rf<4;++rf)
                acc[rf][g] = __builtin_amdgcn_mfma_f32_16x16x32_bf16(a[rf], bb, acc[rf][g], 0,0,0);
        }
    }

    int d = d0 + wd*16 + l16;
    float bi  = b_ih[n*2048 +        d] + b_hh[n*2048 +        d];
    float bff = b_ih[n*2048 +  512 + d] + b_hh[n*2048 +  512 + d];
    float bg  = b_ih[n*2048 + 1024 + d] + b_hh[n*2048 + 1024 + d];
    float bo  = b_ih[n*2048 + 1536 + d] + b_hh[n*2048 + 1536 + d];
    #pragma unroll
    for (int rf=0;rf<4;++rf){
        #pragma unroll
        for (int v=0;v<4;++v){
            int row = b0 + wm*64 + rf*16 + quad*4 + v;
            float gi = acc[rf][0][v] + bi;
            float gf = acc[rf][1][v] + bff;
            float gg = acc[rf][2][v] + bg;
            float go = acc[rf][3][v] + bo;
            size_t gidx = (size_t)row*4096 + n*512 + d;
            float cb = cx[gidx];
            float cn = sigf(gf)*cb + sigf(gi)*ftanh(gg);
            float hn = sigf(go)*ftanh(cn);
            float m  = maskb[row*8+n];
            cx_out[gidx] = (m != 0.f) ? cn : cb;
            hn16[gidx]   = (bf16)hn;
        }
    }
}

// ---------------------------------------------------------------- qkv2 = hn @ mha_w{q,k,v} (MFMA, dbuf)
__global__ __launch_bounds__(256) void k_proj64(const bf16* __restrict__ hn16,
                                                const bf16* __restrict__ wqkvT,
                                                float* __restrict__ qkv2)
{
    int b0 = blockIdx.x*64, n = blockIdx.y, ct = blockIdx.z;
    int t = threadIdx.x, w = t>>6, l = t&63, quad = l>>4, l16 = l&15;
    int wm = w&1, wd = w>>1;
    __shared__ bf16 A_s[2][256*8];
    __shared__ bf16 B_s[2][256*8];
    f32x4 zero = {0.f,0.f,0.f,0.f};
    f32x4 acc[2][2] = {{zero,zero},{zero,zero}};
    const bf16* ab = hn16 + (size_t)n*512;
    const bf16* wb = wqkvT + ((size_t)n*192 + ct*64)*512;

    auto stage = [&](int buf, int k0){
        int row = t>>2, ss = t&3;
        int seg = ss ^ ((row>>1)&3);
        gload16(ab + (size_t)(b0+row)*4096 + k0 + seg*8, &A_s[buf][(w*64)*8]);
        gload16(wb + (size_t)row*512      + k0 + seg*8, &B_s[buf][(w*64)*8]);
    };

    stage(0, 0);
    for (int it=0; it<16; ++it){
        __syncthreads();
        if (it < 15) stage((it+1)&1, (it+1)*32);
        int buf = it&1;
        bf16x8 a[2], bb[2];
        #pragma unroll
        for (int r=0;r<2;++r){
            int row = wm*32 + r*16 + l16;
            int slot = row*4 + (quad ^ ((row>>1)&3));
            a[r] = *(const bf16x8*)&A_s[buf][slot*8];
        }
        #pragma unroll
        for (int c=0;c<2;++c){
            int col = wd*32 + c*16 + l16;
            int slot = col*4 + (quad ^ ((col>>1)&3));
            bb[c] = *(const bf16x8*)&B_s[buf][slot*8];
        }
        #pragma unroll
        for (int r=0;r<2;++r)
            #pragma unroll
            for (int c=0;c<2;++c)
                acc[r][c] = __builtin_amdgcn_mfma_f32_16x16x32_bf16(a[r], bb[c], acc[r][c], 0,0,0);
    }
    #pragma unroll
    for (int c=0;c<2;++c){
        int col = ct*64 + wd*32 + c*16 + l16;
        #pragma unroll
        for (int r=0;r<2;++r)
            #pragma unroll
            for (int v=0;v<4;++v){
                int row = b0 + wm*32 + r*16 + quad*4 + v;
                qkv2[(size_t)row*1536 + n*192 + col] = acc[r][c][v];
            }
    }
}

// ---------------------------------------------------------------- mha attention -> o2 bf16
__global__ __launch_bounds__(256) void k_att2(const float* __restrict__ qkv2,
                                              bf16* __restrict__ o2buf)
{
    int t = threadIdx.x, sb = t>>6, ts = t&63;
    int b = blockIdx.x*4 + sb;
    __shared__ float q_s[4][512];
    __shared__ float k_s[4][512];
    __shared__ float v_s[4][512];
    __shared__ float at_s[4][64];
    #pragma unroll
    for (int r=0;r<8;++r){
        int i = ts + r*64;
        int n = i>>6, e = i&63;
        const float* src = qkv2 + (size_t)b*1536 + n*192;
        q_s[sb][i] = src[e];
        k_s[sb][i] = src[64+e];
        v_s[sb][i] = src[128+e];
    }
    __syncthreads();
    {
        int n = ts>>3, j = ts&7;
        float s = 0.f;
        const float* q = &q_s[sb][n*64];
        const float* k = &k_s[sb][j*64];
        for (int e=0;e<64;++e) s += q[e]*k[e];
        at_s[sb][ts] = s*0.125f;
    }
    __syncthreads();
    if (ts < 8){
        float m = at_s[sb][ts*8];
        for (int j=1;j<8;++j) m = fmaxf(m, at_s[sb][ts*8+j]);
        float ex[8]; float sum=0.f;
        for (int j=0;j<8;++j){ ex[j]=__expf(at_s[sb][ts*8+j]-m); sum+=ex[j]; }
        float inv = 1.f/sum;
        for (int j=0;j<8;++j) at_s[sb][ts*8+j] = ex[j]*inv;
    }
    __syncthreads();
    #pragma unroll
    for (int r=0;r<8;++r){
        int i = ts + r*64;
        int n = i>>6, e = i&63;
        float s = 0.f;
        #pragma unroll
        for (int j=0;j<8;++j) s += at_s[sb][n*8+j]*v_s[sb][j*64+e];
        o2buf[(size_t)b*512 + i] = (bf16)s;
    }
}

// ---------------------------------------------------------------- hx_out = mask ? hn + sig(g)*tanh(f) : hx
// 2 ct tiles per block: grid (128, 8)
__global__ __launch_bounds__(256) void k_fcgate(const bf16* __restrict__ o2buf,
                                                const bf16* __restrict__ fcgT,
                                                const float* __restrict__ fc_b,
                                                const float* __restrict__ gate_b,
                                                const bf16* __restrict__ hn16,
                                                const float* __restrict__ hx,
                                                const float* __restrict__ maskb,
                                                float* __restrict__ hx_out)
{
    int bx = blockIdx.x, ct0 = blockIdx.y*2;
    int t = threadIdx.x, w = t>>6, l = t&63, quad = l>>4, l16 = l&15;
    __shared__ bf16 A_s[64*72];
    __shared__ bf16 W_s[2][64*72];
    #pragma unroll
    for (int j=0;j<2;++j){
        int c = t + j*256;
        int row = c>>3, seg = c&7;
        *(bf16x8*)&A_s[row*72 + seg*8] = *(const bf16x8*)&o2buf[((size_t)bx*64+row)*64 + seg*8];
        *(bf16x8*)&W_s[0][row*72 + seg*8] = *(const bf16x8*)&fcgT[((size_t)ct0*64+row)*64 + seg*8];
        *(bf16x8*)&W_s[1][row*72 + seg*8] = *(const bf16x8*)&fcgT[((size_t)(ct0+1)*64+row)*64 + seg*8];
    }
    __syncthreads();
    f32x4 zero = {0.f,0.f,0.f,0.f};
    #pragma unroll
    for (int cc=0; cc<2; ++cc){
        int ct = ct0 + cc;
        f32x4 acc[4] = {zero,zero,zero,zero};
        #pragma unroll
        for (int k0=0;k0<64;k0+=32){
            bf16x8 a = *(const bf16x8*)&A_s[(w*16+l16)*72 + k0 + quad*8];
            #pragma unroll
            for (int c=0;c<4;++c){
                bf16x8 bb = *(const bf16x8*)&W_s[cc][(c*16+l16)*72 + k0 + quad*8];
                acc[c] = __builtin_amdgcn_mfma_f32_16x16x32_bf16(a, bb, acc[c], 0,0,0);
            }
        }
        #pragma unroll
        for (int c=0;c<2;++c){
            int d = ct*32 + c*16 + l16;
            float fb = fc_b[d], gb = gate_b[d];
            #pragma unroll
            for (int v=0;v<4;++v){
                int row = bx*64 + w*16 + quad*4 + v;
                int b = row>>3, n = row&7;
                size_t idx = (size_t)b*4096 + n*512 + d;
                float f = acc[c][v]   + fb;
                float g = acc[c+2][v] + gb;
                float hn = (float)hn16[idx];
                float m = maskb[row];
                hx_out[idx] = (m != 0.f) ? (hn + sigf(g)*ftanh(f)) : hx[idx];
            }
        }
    }
}

// ----------------------------------------------------------------
extern "C" void kernel_launch(void* const* d_in, const int* in_sizes, int n_in,
                              void* d_out, int out_size, void* d_ws, size_t ws_size,
                              hipStream_t stream)
{
    const float* inp       = (const float*)d_in[0];
    const float* hx        = (const float*)d_in[1];
    const float* cx        = (const float*)d_in[2];
    const float* ia_wq     = (const float*)d_in[3];
    const float* ia_wk     = (const float*)d_in[4];
    const float* ia_wv     = (const float*)d_in[5];
    const float* ia_fc_w   = (const float*)d_in[6];
    const float* ia_fc_b   = (const float*)d_in[7];
    const float* mha_wq    = (const float*)d_in[8];
    const float* mha_wk    = (const float*)d_in[9];
    const float* mha_wv    = (const float*)d_in[10];
    const float* mha_fc_w  = (const float*)d_in[11];
    const float* mha_fc_b  = (const float*)d_in[12];
    const float* mha_gate_w= (const float*)d_in[13];
    const float* mha_gate_b= (const float*)d_in[14];
    const float* w_ih      = (const float*)d_in[15];
    const float* w_hh      = (const float*)d_in[16];
    const float* b_ih      = (const float*)d_in[17];
    const float* b_hh      = (const float*)d_in[18];

    float* hx_out  = (float*)d_out;
    float* cx_out  = hx_out + (size_t)B_*NHID_;
    float* mask_out= cx_out + (size_t)B_*NHID_;

    char* p = (char*)d_ws;
    bf16* wT     = (bf16*)p;               p += (size_t)8*2048*1024*2;   // 32 MB
    bf16* hb16   = (bf16*)p;               p += (size_t)B_*NHID_*2;      // 8 MB
    bf16* xb16   = (bf16*)p;               p += (size_t)B_*NHID_*2;      // 8 MB
    bf16* hn16   = (bf16*)p;               p += (size_t)B_*NHID_*2;      // 8 MB
    bf16* wqkvT  = (bf16*)p;               p += (size_t)8*192*512*2;     // 1.5 MB
    bf16* iafcT  = (bf16*)p;               p += (size_t)512*64*2;        // 64 KB
    bf16* fcgT   = (bf16*)p;               p += (size_t)1024*64*2;       // 128 KB
    float* qbuf  = (float*)p;              p += (size_t)B_*512*4;        // 2 MB
    float* kbuf  = (float*)p;              p += (size_t)B_*256*4;        // 1 MB
    float* vbuf  = (float*)p;              p += (size_t)B_*256*4;        // 1 MB
    bf16* obuf   = (bf16*)p;               p += (size_t)B_*8*64*2;       // 1 MB
    bf16* o2buf  = (bf16*)p;               p += (size_t)B_*8*64*2;       // 1 MB
    float* qkv2  = (float*)p;              p += (size_t)B_*1536*4;       // 6 MB
    float* maskb = (float*)p;              p += (size_t)B_*8*4;          // 32 KB

    hipLaunchKernelGGL(k_prep, dim3(11648), dim3(256), 0, stream,
                       w_ih, w_hh, hx, mha_wq, mha_wk, mha_wv, ia_fc_w, mha_fc_w, mha_gate_w,
                       wT, hb16, wqkvT, iafcT, fcgT);
    hipLaunchKernelGGL(k_qkv, dim3(32,12), dim3(256), 0, stream,
                       hx, inp, ia_wq, ia_wk, ia_wv, qbuf, kbuf, vbuf);
    hipLaunchKernelGGL(k_score, dim3(256), dim3(256), 0, stream,
                       qbuf, kbuf, vbuf, obuf, maskb, mask_out);
    hipLaunchKernelGGL(k_fc_ia, dim3(128,8), dim3(256), 0, stream, obuf, iafcT, ia_fc_b, xb16);
    hipLaunchKernelGGL(k_lstm, dim3(1024), dim3(256), 0, stream,
                       xb16, hb16, wT, b_ih, b_hh, cx, maskb, cx_out, hn16);
    hipLaunchKernelGGL(k_proj64, dim3(16,8,3), dim3(256), 0, stream, hn16, wqkvT, qkv2);
    hipLaunchKernelGGL(k_att2, dim3(256), dim3(256), 0, stream, qkv2, o2buf);
    hipLaunchKernelGGL(k_fcgate, dim3(128,8), dim3(256), 0, stream,
                       o2buf, fcgT, mha_fc_b, mha_gate_b, hn16, hx, maskb, hx_out);
}